// Round 1
// baseline (992.768 us; speedup 1.0000x reference)
//
#include <hip/hip_runtime.h>

// SimSiam: N=8192, D=256, H=128, fp32.
// loss = -0.5*(mean(pxn·yn_row) + mean(pyn·xn_row))
// acc_x = 0.5*mean(colargmax(sim_x)==gold) + mean(rowargmax(sim_x)==gold), sim_x = pxn @ yn^T
// acc_y likewise with sim_y = pyn @ xn^T

static constexpr int N = 8192;
static constexpr int D = 256;
static constexpr int H = 128;

__device__ __forceinline__ unsigned f2ord(float f) {
    unsigned u = __float_as_uint(f);
    return (u & 0x80000000u) ? ~u : (u | 0x80000000u);
}
__device__ __forceinline__ unsigned long long umax64(unsigned long long a, unsigned long long b) {
    return a > b ? a : b;
}

// ---------------------------------------------------------------------------
// Kernel 1: Pn = rownormalize(relu(V@W1 + b1)@W2 + b2).  32 rows per block.
// ---------------------------------------------------------------------------
static constexpr int MLP_ROWS = 32;

__global__ __launch_bounds__(256) void mlp_norm_kernel(
    const float* __restrict__ V, const float* __restrict__ W1, const float* __restrict__ b1,
    const float* __restrict__ W2, const float* __restrict__ b2, float* __restrict__ Pn)
{
    __shared__ float sV[MLP_ROWS][D + 4];   // 33.3 KB (aliased as P storage later)
    __shared__ float sH[MLP_ROWS][H + 4];   // 16.9 KB
    __shared__ float sNrm[MLP_ROWS];

    const int t = threadIdx.x;
    const int rowBase = blockIdx.x * MLP_ROWS;

    // load V tile (32 x 256 floats) vectorized
    for (int i = t; i < MLP_ROWS * (D / 4); i += 256) {
        int r = i >> 6;          // i / 64
        int c4 = i & 63;
        float4 v = *reinterpret_cast<const float4*>(&V[(size_t)(rowBase + r) * D + c4 * 4]);
        sV[r][c4 * 4 + 0] = v.x; sV[r][c4 * 4 + 1] = v.y;
        sV[r][c4 * 4 + 2] = v.z; sV[r][c4 * 4 + 3] = v.w;
    }
    __syncthreads();

    // H = relu(V@W1 + b1): thread -> column c = t&127, rows r0..r0+15
    {
        const int c = t & (H - 1);
        const int r0 = (t >> 7) * 16;
        float acc[16];
#pragma unroll
        for (int i = 0; i < 16; ++i) acc[i] = 0.f;
        for (int k4 = 0; k4 < D / 4; ++k4) {
            float w0 = W1[(k4 * 4 + 0) * H + c];
            float w1 = W1[(k4 * 4 + 1) * H + c];
            float w2 = W1[(k4 * 4 + 2) * H + c];
            float w3 = W1[(k4 * 4 + 3) * H + c];
#pragma unroll
            for (int i = 0; i < 16; ++i) {
                float4 v = *reinterpret_cast<const float4*>(&sV[r0 + i][k4 * 4]);
                acc[i] = fmaf(v.w, w3, fmaf(v.z, w2, fmaf(v.y, w1, fmaf(v.x, w0, acc[i]))));
            }
        }
        float bb = b1[c];
#pragma unroll
        for (int i = 0; i < 16; ++i) {
            float h = acc[i] + bb;
            sH[r0 + i][c] = h > 0.f ? h : 0.f;
        }
    }
    __syncthreads();

    // P = H@W2 + b2: thread -> column c = t, all 32 rows. Store P into sV (V is dead).
    {
        const int c = t;
        float acc[MLP_ROWS];
#pragma unroll
        for (int i = 0; i < MLP_ROWS; ++i) acc[i] = 0.f;
        for (int k4 = 0; k4 < H / 4; ++k4) {
            float w0 = W2[(k4 * 4 + 0) * D + c];
            float w1 = W2[(k4 * 4 + 1) * D + c];
            float w2 = W2[(k4 * 4 + 2) * D + c];
            float w3 = W2[(k4 * 4 + 3) * D + c];
#pragma unroll
            for (int i = 0; i < MLP_ROWS; ++i) {
                float4 v = *reinterpret_cast<const float4*>(&sH[i][k4 * 4]);
                acc[i] = fmaf(v.w, w3, fmaf(v.z, w2, fmaf(v.y, w1, fmaf(v.x, w0, acc[i]))));
            }
        }
        float bb = b2[c];
        __syncthreads();   // everyone done reading sV before overwrite
#pragma unroll
        for (int i = 0; i < MLP_ROWS; ++i) sV[i][c] = acc[i] + bb;
    }
    __syncthreads();

    // row norms (4 waves, wave handles rows wave, wave+4, ...)
    {
        const int wave = t >> 6, lane = t & 63;
        for (int r = wave; r < MLP_ROWS; r += 4) {
            float s = 0.f;
#pragma unroll
            for (int c = 0; c < D / 64; ++c) {
                float v = sV[r][lane + c * 64];
                s = fmaf(v, v, s);
            }
#pragma unroll
            for (int off = 32; off > 0; off >>= 1) s += __shfl_down(s, off);
            if (lane == 0) sNrm[r] = s;
        }
    }
    __syncthreads();

    for (int i = t; i < MLP_ROWS * (D / 4); i += 256) {
        int r = i >> 6;
        int c4 = i & 63;
        float scale = 1.0f / fmaxf(sqrtf(sNrm[r]), 1e-12f);
        float4 v;
        v.x = sV[r][c4 * 4 + 0] * scale; v.y = sV[r][c4 * 4 + 1] * scale;
        v.z = sV[r][c4 * 4 + 2] * scale; v.w = sV[r][c4 * 4 + 3] * scale;
        *reinterpret_cast<float4*>(&Pn[(size_t)(rowBase + r) * D + c4 * 4]) = v;
    }
}

// ---------------------------------------------------------------------------
// Kernel 2: plain row L2-normalize. One wave per row.
// ---------------------------------------------------------------------------
__global__ __launch_bounds__(256) void rownorm_kernel(const float* __restrict__ V, float* __restrict__ Vn)
{
    const int wave = threadIdx.x >> 6, lane = threadIdx.x & 63;
    const int row = blockIdx.x * 4 + wave;
    float4 v = *reinterpret_cast<const float4*>(&V[(size_t)row * D + lane * 4]);
    float s = fmaf(v.x, v.x, fmaf(v.y, v.y, fmaf(v.z, v.z, v.w * v.w)));
#pragma unroll
    for (int off = 32; off > 0; off >>= 1) s += __shfl_down(s, off);
    s = __shfl(s, 0);
    float scale = 1.0f / fmaxf(sqrtf(s), 1e-12f);
    float4 o; o.x = v.x * scale; o.y = v.y * scale; o.z = v.z * scale; o.w = v.w * scale;
    *reinterpret_cast<float4*>(&Vn[(size_t)row * D + lane * 4]) = o;
}

// ---------------------------------------------------------------------------
// Kernel 3: streaming sim = A@B^T with row/col argmax via atomicMax on
// (f2ord(value)<<32 | ~index) keys. 128x128 tile / block, 8x8 per thread.
// ---------------------------------------------------------------------------
static constexpr int TM = 128;
static constexpr int TN = 128;
static constexpr int BK = 32;

__global__ __launch_bounds__(256) void sim_argmax_kernel(
    const float* __restrict__ A, const float* __restrict__ B,
    unsigned long long* __restrict__ rowKeys, unsigned long long* __restrict__ colKeys)
{
    __shared__ float sA[BK][TM + 4];
    __shared__ float sB[BK][TN + 4];
    __shared__ unsigned long long kbuf[128][16];

    const int t = threadIdx.x;
    const int tx = t & 15, ty = t >> 4;
    const int rowBase = blockIdx.x * TM, colBase = blockIdx.y * TN;

    float acc[8][8];
#pragma unroll
    for (int i = 0; i < 8; ++i)
#pragma unroll
        for (int j = 0; j < 8; ++j) acc[i][j] = 0.f;

    for (int kt = 0; kt < D / BK; ++kt) {
        const int kB = kt * BK;
#pragma unroll
        for (int i = 0; i < 4; ++i) {
            int id = t + i * 256;        // 0..1023
            int m = id >> 3, k4 = id & 7;
            float4 va = *reinterpret_cast<const float4*>(&A[(size_t)(rowBase + m) * D + kB + k4 * 4]);
            sA[k4 * 4 + 0][m] = va.x; sA[k4 * 4 + 1][m] = va.y;
            sA[k4 * 4 + 2][m] = va.z; sA[k4 * 4 + 3][m] = va.w;
            float4 vb = *reinterpret_cast<const float4*>(&B[(size_t)(colBase + m) * D + kB + k4 * 4]);
            sB[k4 * 4 + 0][m] = vb.x; sB[k4 * 4 + 1][m] = vb.y;
            sB[k4 * 4 + 2][m] = vb.z; sB[k4 * 4 + 3][m] = vb.w;
        }
        __syncthreads();

#pragma unroll 4
        for (int k = 0; k < BK; ++k) {
            float4 aLo = *reinterpret_cast<const float4*>(&sA[k][ty * 4]);
            float4 aHi = *reinterpret_cast<const float4*>(&sA[k][64 + ty * 4]);
            float4 bLo = *reinterpret_cast<const float4*>(&sB[k][tx * 4]);
            float4 bHi = *reinterpret_cast<const float4*>(&sB[k][64 + tx * 4]);
            float a[8] = {aLo.x, aLo.y, aLo.z, aLo.w, aHi.x, aHi.y, aHi.z, aHi.w};
            float b[8] = {bLo.x, bLo.y, bLo.z, bLo.w, bHi.x, bHi.y, bHi.z, bHi.w};
#pragma unroll
            for (int i = 0; i < 8; ++i)
#pragma unroll
                for (int j = 0; j < 8; ++j)
                    acc[i][j] = fmaf(a[i], b[j], acc[i][j]);
        }
        __syncthreads();
    }

    // ---- row argmax (max over cols j), first-index tie-break via ~index ----
#pragma unroll
    for (int i = 0; i < 8; ++i) {
        int m = (i < 4) ? (ty * 4 + i) : (64 + ty * 4 + (i - 4));
        unsigned long long best = 0ULL;
#pragma unroll
        for (int j = 0; j < 8; ++j) {
            int n = (j < 4) ? (tx * 4 + j) : (64 + tx * 4 + (j - 4));
            unsigned long long key =
                ((unsigned long long)f2ord(acc[i][j]) << 32) | (unsigned)(~(unsigned)(colBase + n));
            best = umax64(best, key);
        }
        kbuf[m][tx] = best;
    }
    __syncthreads();
    if (t < 128) {
        unsigned long long best = kbuf[t][0];
#pragma unroll
        for (int q = 1; q < 16; ++q) best = umax64(best, kbuf[t][q]);
        atomicMax(&rowKeys[rowBase + t], best);
    }
    __syncthreads();

    // ---- col argmax (max over rows i) ----
#pragma unroll
    for (int j = 0; j < 8; ++j) {
        int n = (j < 4) ? (tx * 4 + j) : (64 + tx * 4 + (j - 4));
        unsigned long long best = 0ULL;
#pragma unroll
        for (int i = 0; i < 8; ++i) {
            int m = (i < 4) ? (ty * 4 + i) : (64 + ty * 4 + (i - 4));
            unsigned long long key =
                ((unsigned long long)f2ord(acc[i][j]) << 32) | (unsigned)(~(unsigned)(rowBase + m));
            best = umax64(best, key);
        }
        kbuf[n][ty] = best;
    }
    __syncthreads();
    if (t < 128) {
        unsigned long long best = kbuf[t][0];
#pragma unroll
        for (int q = 1; q < 16; ++q) best = umax64(best, kbuf[t][q]);
        atomicMax(&colKeys[colBase + t], best);
    }
}

// ---------------------------------------------------------------------------
// Kernel 4: loss partials. Block = 256 rows, wave = 64 rows -> 128 partials.
// ---------------------------------------------------------------------------
__global__ __launch_bounds__(256) void loss_partial_kernel(
    const float* __restrict__ A, const float* __restrict__ B, float* __restrict__ partials)
{
    const int wave = threadIdx.x >> 6, lane = threadIdx.x & 63;
    const int r0 = blockIdx.x * 256 + wave * 64;
    float acc = 0.f;
    for (int r = r0; r < r0 + 64; ++r) {
        float4 a = *reinterpret_cast<const float4*>(&A[(size_t)r * D + lane * 4]);
        float4 b = *reinterpret_cast<const float4*>(&B[(size_t)r * D + lane * 4]);
        acc += fmaf(a.x, b.x, fmaf(a.y, b.y, fmaf(a.z, b.z, a.w * b.w)));
    }
#pragma unroll
    for (int off = 32; off > 0; off >>= 1) acc += __shfl_down(acc, off);
    if (lane == 0) partials[blockIdx.x * 4 + wave] = acc;
}

// ---------------------------------------------------------------------------
// Kernel 5: finalize — deterministic counts + loss.
// ---------------------------------------------------------------------------
static constexpr int LOSS_PARTS = 128;

__global__ __launch_bounds__(256) void finalize_kernel(
    const unsigned long long* __restrict__ rkx, const unsigned long long* __restrict__ ckx,
    const unsigned long long* __restrict__ rky, const unsigned long long* __restrict__ cky,
    const float* __restrict__ parts, float* __restrict__ out)
{
    __shared__ int cnt[4];
    const int t = threadIdx.x;
    if (t < 4) cnt[t] = 0;
    __syncthreads();
    int c0 = 0, c1 = 0, c2 = 0, c3 = 0;
    for (int i = t; i < N; i += 256) {
        c0 += ((~(unsigned)rkx[i]) == (unsigned)i);
        c1 += ((~(unsigned)ckx[i]) == (unsigned)i);
        c2 += ((~(unsigned)rky[i]) == (unsigned)i);
        c3 += ((~(unsigned)cky[i]) == (unsigned)i);
    }
    atomicAdd(&cnt[0], c0);
    atomicAdd(&cnt[1], c1);
    atomicAdd(&cnt[2], c2);
    atomicAdd(&cnt[3], c3);
    __syncthreads();
    if (t == 0) {
        double sx = 0.0, sy = 0.0;
        for (int i = 0; i < LOSS_PARTS; ++i) { sx += (double)parts[i]; sy += (double)parts[LOSS_PARTS + i]; }
        float invN = 1.0f / (float)N;
        out[0] = (float)(-0.5 * (sx + sy) / (double)N);
        out[1] = 0.5f * ((float)cnt[1] * invN) + (float)cnt[0] * invN;   // acc_x: 0.5*axis0 + axis1
        out[2] = 0.5f * ((float)cnt[3] * invN) + (float)cnt[2] * invN;   // acc_y
    }
}

// ---------------------------------------------------------------------------
extern "C" void kernel_launch(void* const* d_in, const int* in_sizes, int n_in,
                              void* d_out, int out_size, void* d_ws, size_t ws_size,
                              hipStream_t stream)
{
    (void)in_sizes; (void)n_in; (void)out_size; (void)ws_size;
    const float* x  = (const float*)d_in[0];
    const float* y  = (const float*)d_in[1];
    const float* W1 = (const float*)d_in[2];
    const float* b1 = (const float*)d_in[3];
    const float* W2 = (const float*)d_in[4];
    const float* b2 = (const float*)d_in[5];
    float* out = (float*)d_out;

    float* pxn = (float*)d_ws;                       // 8 MB
    float* pyn = pxn + (size_t)N * D;                // 8 MB
    float* xn  = pyn + (size_t)N * D;                // 8 MB
    float* yn  = xn  + (size_t)N * D;                // 8 MB
    unsigned long long* keys = (unsigned long long*)(yn + (size_t)N * D);  // 256 KB
    unsigned long long* rkx = keys + 0 * N;
    unsigned long long* ckx = keys + 1 * N;
    unsigned long long* rky = keys + 2 * N;
    unsigned long long* cky = keys + 3 * N;
    float* parts = (float*)(keys + 4 * N);           // 256 floats

    hipMemsetAsync(keys, 0, 4 * (size_t)N * sizeof(unsigned long long), stream);

    mlp_norm_kernel<<<N / MLP_ROWS, 256, 0, stream>>>(x, W1, b1, W2, b2, pxn);
    mlp_norm_kernel<<<N / MLP_ROWS, 256, 0, stream>>>(y, W1, b1, W2, b2, pyn);
    rownorm_kernel<<<N / 4, 256, 0, stream>>>(x, xn);
    rownorm_kernel<<<N / 4, 256, 0, stream>>>(y, yn);

    dim3 simGrid(N / TM, N / TN);
    sim_argmax_kernel<<<simGrid, 256, 0, stream>>>(pxn, yn, rkx, ckx);
    sim_argmax_kernel<<<simGrid, 256, 0, stream>>>(pyn, xn, rky, cky);

    loss_partial_kernel<<<32, 256, 0, stream>>>(pxn, yn, parts);
    loss_partial_kernel<<<32, 256, 0, stream>>>(pyn, xn, parts + LOSS_PARTS);

    finalize_kernel<<<1, 256, 0, stream>>>(rkx, ckx, rky, cky, parts, out);
}

// Round 2
// 713.519 us; speedup vs baseline: 1.3914x; 1.3914x over previous
//
#include <hip/hip_runtime.h>

// SimSiam: N=8192, D=256, H=128, fp32 in/out.
// Heavy part (2x 8192x8192x256 sim+argmax) runs on bf16 MFMA via split-fp32
// (hi/lo bf16 planes, 3-term product), everything else fp32 vector.

static constexpr int N = 8192;
static constexpr int D = 256;
static constexpr int H = 128;

typedef __attribute__((ext_vector_type(8))) short s16x8;
typedef __attribute__((ext_vector_type(4))) float fp32x4;

__device__ __forceinline__ unsigned f2ord(float f) {
    unsigned u = __float_as_uint(f);
    return (u & 0x80000000u) ? ~u : (u | 0x80000000u);
}
__device__ __forceinline__ unsigned long long umax64(unsigned long long a, unsigned long long b) {
    return a > b ? a : b;
}
__device__ __forceinline__ unsigned short bf16_rtne(float f) {
    unsigned u = __float_as_uint(f);
    unsigned r = 0x7FFFu + ((u >> 16) & 1u);
    return (unsigned short)((u + r) >> 16);
}
__device__ __forceinline__ float bf_f(unsigned short h) {
    return __uint_as_float((unsigned)h << 16);
}
__device__ __forceinline__ void split_store(float f, unsigned short* h, unsigned short* l) {
    unsigned short hb = bf16_rtne(f);
    *h = hb;
    *l = bf16_rtne(f - bf_f(hb));
}
__device__ __forceinline__ void gload16(const unsigned short* g, void* lds) {
    __builtin_amdgcn_global_load_lds(
        (const __attribute__((address_space(1))) unsigned int*)g,
        (__attribute__((address_space(3))) unsigned int*)lds, 16, 0, 0);
}

// ---------------------------------------------------------------------------
// Kernel 1: Pn = rownormalize(relu(V@W1+b1)@W2+b2) -> hi/lo bf16 planes.
// ---------------------------------------------------------------------------
static constexpr int MLP_ROWS = 32;

__global__ __launch_bounds__(256) void mlp_norm_kernel(
    const float* __restrict__ V, const float* __restrict__ W1, const float* __restrict__ b1,
    const float* __restrict__ W2, const float* __restrict__ b2,
    unsigned short* __restrict__ Ph, unsigned short* __restrict__ Pl)
{
    __shared__ float sV[MLP_ROWS][D + 4];
    __shared__ float sH[MLP_ROWS][H + 4];
    __shared__ float sNrm[MLP_ROWS];

    const int t = threadIdx.x;
    const int rowBase = blockIdx.x * MLP_ROWS;

    for (int i = t; i < MLP_ROWS * (D / 4); i += 256) {
        int r = i >> 6, c4 = i & 63;
        float4 v = *reinterpret_cast<const float4*>(&V[(size_t)(rowBase + r) * D + c4 * 4]);
        sV[r][c4 * 4 + 0] = v.x; sV[r][c4 * 4 + 1] = v.y;
        sV[r][c4 * 4 + 2] = v.z; sV[r][c4 * 4 + 3] = v.w;
    }
    __syncthreads();

    {   // H = relu(V@W1 + b1)
        const int c = t & (H - 1);
        const int r0 = (t >> 7) * 16;
        float acc[16];
#pragma unroll
        for (int i = 0; i < 16; ++i) acc[i] = 0.f;
        for (int k4 = 0; k4 < D / 4; ++k4) {
            float w0 = W1[(k4 * 4 + 0) * H + c];
            float w1 = W1[(k4 * 4 + 1) * H + c];
            float w2 = W1[(k4 * 4 + 2) * H + c];
            float w3 = W1[(k4 * 4 + 3) * H + c];
#pragma unroll
            for (int i = 0; i < 16; ++i) {
                float4 v = *reinterpret_cast<const float4*>(&sV[r0 + i][k4 * 4]);
                acc[i] = fmaf(v.w, w3, fmaf(v.z, w2, fmaf(v.y, w1, fmaf(v.x, w0, acc[i]))));
            }
        }
        float bb = b1[c];
#pragma unroll
        for (int i = 0; i < 16; ++i) {
            float h = acc[i] + bb;
            sH[r0 + i][c] = h > 0.f ? h : 0.f;
        }
    }
    __syncthreads();

    {   // P = H@W2 + b2 -> back into sV
        const int c = t;
        float acc[MLP_ROWS];
#pragma unroll
        for (int i = 0; i < MLP_ROWS; ++i) acc[i] = 0.f;
        for (int k4 = 0; k4 < H / 4; ++k4) {
            float w0 = W2[(k4 * 4 + 0) * D + c];
            float w1 = W2[(k4 * 4 + 1) * D + c];
            float w2 = W2[(k4 * 4 + 2) * D + c];
            float w3 = W2[(k4 * 4 + 3) * D + c];
#pragma unroll
            for (int i = 0; i < MLP_ROWS; ++i) {
                float4 v = *reinterpret_cast<const float4*>(&sH[i][k4 * 4]);
                acc[i] = fmaf(v.w, w3, fmaf(v.z, w2, fmaf(v.y, w1, fmaf(v.x, w0, acc[i]))));
            }
        }
        float bb = b2[c];
        __syncthreads();
#pragma unroll
        for (int i = 0; i < MLP_ROWS; ++i) sV[i][c] = acc[i] + bb;
    }
    __syncthreads();

    {   // row norms
        const int wave = t >> 6, lane = t & 63;
        for (int r = wave; r < MLP_ROWS; r += 4) {
            float s = 0.f;
#pragma unroll
            for (int c = 0; c < D / 64; ++c) {
                float v = sV[r][lane + c * 64];
                s = fmaf(v, v, s);
            }
#pragma unroll
            for (int off = 32; off > 0; off >>= 1) s += __shfl_down(s, off);
            if (lane == 0) sNrm[r] = s;
        }
    }
    __syncthreads();

    for (int i = t; i < MLP_ROWS * (D / 4); i += 256) {
        int r = i >> 6, c4 = i & 63;
        float scale = 1.0f / fmaxf(sqrtf(sNrm[r]), 1e-12f);
        ushort4 h, l;
        float f0 = sV[r][c4 * 4 + 0] * scale;
        float f1 = sV[r][c4 * 4 + 1] * scale;
        float f2 = sV[r][c4 * 4 + 2] * scale;
        float f3 = sV[r][c4 * 4 + 3] * scale;
        split_store(f0, &h.x, &l.x);
        split_store(f1, &h.y, &l.y);
        split_store(f2, &h.z, &l.z);
        split_store(f3, &h.w, &l.w);
        size_t base = (size_t)(rowBase + r) * D + c4 * 4;
        *reinterpret_cast<ushort4*>(&Ph[base]) = h;
        *reinterpret_cast<ushort4*>(&Pl[base]) = l;
    }
}

// ---------------------------------------------------------------------------
// Kernel 2: plain row L2-normalize -> hi/lo bf16 planes. One wave per row.
// ---------------------------------------------------------------------------
__global__ __launch_bounds__(256) void rownorm_kernel(
    const float* __restrict__ V, unsigned short* __restrict__ Vh, unsigned short* __restrict__ Vl)
{
    const int wave = threadIdx.x >> 6, lane = threadIdx.x & 63;
    const int row = blockIdx.x * 4 + wave;
    float4 v = *reinterpret_cast<const float4*>(&V[(size_t)row * D + lane * 4]);
    float s = fmaf(v.x, v.x, fmaf(v.y, v.y, fmaf(v.z, v.z, v.w * v.w)));
#pragma unroll
    for (int off = 32; off > 0; off >>= 1) s += __shfl_down(s, off);
    s = __shfl(s, 0);
    float scale = 1.0f / fmaxf(sqrtf(s), 1e-12f);
    ushort4 h, l;
    split_store(v.x * scale, &h.x, &l.x);
    split_store(v.y * scale, &h.y, &l.y);
    split_store(v.z * scale, &h.z, &l.z);
    split_store(v.w * scale, &h.w, &l.w);
    size_t base = (size_t)row * D + lane * 4;
    *reinterpret_cast<ushort4*>(&Vh[base]) = h;
    *reinterpret_cast<ushort4*>(&Vl[base]) = l;
}

// ---------------------------------------------------------------------------
// Kernel 3: sim = (Ah+Al)@(Bh+Bl)^T via 3-term bf16 MFMA, streaming argmax.
// 128x128 tile, 4 waves (2x2 of 64x64), BK=32, virtual K = 768.
// LDS layout: fragment slots, slot(kq, m) = kq*128 + m, 16B each.
// ---------------------------------------------------------------------------
__global__ __launch_bounds__(256) void sim_argmax_mfma(
    const unsigned short* __restrict__ Ah, const unsigned short* __restrict__ Al,
    const unsigned short* __restrict__ Bh, const unsigned short* __restrict__ Bl,
    unsigned long long* __restrict__ rowKeys, unsigned long long* __restrict__ colKeys)
{
    __shared__ s16x8 sA[2][512];   // 16 KB
    __shared__ s16x8 sB[2][512];   // 16 KB

    const int t = threadIdx.x;
    const int w = t >> 6, lane = t & 63;
    const int wr = w >> 1, wc = w & 1;

    // bijective XCD swizzle: 4096 blocks, 8 XCDs, 512 per XCD
    int bid = blockIdx.x;
    int swz = (bid & 7) * 512 + (bid >> 3);
    const int rowBase = (swz & 63) * 128;   // fast -> A streams, B chunk L2-resident
    const int colBase = (swz >> 6) * 128;

    fp32x4 acc[4][4];
#pragma unroll
    for (int i = 0; i < 4; ++i)
#pragma unroll
        for (int j = 0; j < 4; ++j) acc[i][j] = (fp32x4){0.f, 0.f, 0.f, 0.f};

    // stage one K-tile: 8 A-instr + 8 B-instr of 1KB, wave w does i in {w, w+4}
#define STAGE(buf, Ap, Bp, kb)                                                                     \
    do {                                                                                           \
        const int i0 = w, i1 = w + 4;                                                              \
        gload16((Ap) + (size_t)(rowBase + (i0 & 1) * 64 + lane) * D + (kb) + (i0 >> 1) * 8,        \
                (void*)&sA[buf][i0 * 64]);                                                         \
        gload16((Ap) + (size_t)(rowBase + (i1 & 1) * 64 + lane) * D + (kb) + (i1 >> 1) * 8,        \
                (void*)&sA[buf][i1 * 64]);                                                         \
        gload16((Bp) + (size_t)(colBase + (i0 & 1) * 64 + lane) * D + (kb) + (i0 >> 1) * 8,        \
                (void*)&sB[buf][i0 * 64]);                                                         \
        gload16((Bp) + (size_t)(colBase + (i1 & 1) * 64 + lane) * D + (kb) + (i1 >> 1) * 8,        \
                (void*)&sB[buf][i1 * 64]);                                                         \
    } while (0)

    STAGE(0, Ah, Bh, 0);

    const int gk = (lane >> 4) * 128 + (lane & 15);   // fragment slot base

    for (int vt = 0; vt < 24; ++vt) {
        const int cur = vt & 1;
        __syncthreads();   // staging of buf[cur] done; prior reads of buf[cur^1] done
        if (vt < 23) {
            int v2 = vt + 1;
            int p2 = v2 >> 3;
            int kb2 = (v2 & 7) * 32;
            const unsigned short* Ap2 = (p2 == 1) ? Al : Ah;
            const unsigned short* Bp2 = (p2 == 2) ? Bl : Bh;
            STAGE(cur ^ 1, Ap2, Bp2, kb2);
        }
        s16x8 af[4], bf[4];
#pragma unroll
        for (int fm = 0; fm < 4; ++fm) af[fm] = sA[cur][gk + wr * 64 + fm * 16];
#pragma unroll
        for (int fn = 0; fn < 4; ++fn) bf[fn] = sB[cur][gk + wc * 64 + fn * 16];
#pragma unroll
        for (int fm = 0; fm < 4; ++fm)
#pragma unroll
            for (int fn = 0; fn < 4; ++fn)
                acc[fm][fn] = __builtin_amdgcn_mfma_f32_16x16x32_bf16(af[fm], bf[fn], acc[fm][fn], 0, 0, 0);
    }
#undef STAGE

    // ---- row argmax: C/D map col=lane&15, row=(lane>>4)*4+r (m89/m91) ----
#pragma unroll
    for (int fm = 0; fm < 4; ++fm) {
#pragma unroll
        for (int r = 0; r < 4; ++r) {
            int grow = rowBase + wr * 64 + fm * 16 + (lane >> 4) * 4 + r;
            unsigned long long key = 0ULL;
#pragma unroll
            for (int fn = 0; fn < 4; ++fn) {
                int gcol = colBase + wc * 64 + fn * 16 + (lane & 15);
                unsigned long long k2 =
                    ((unsigned long long)f2ord(acc[fm][fn][r]) << 32) | (unsigned)(~(unsigned)gcol);
                key = umax64(key, k2);
            }
#pragma unroll
            for (int off = 1; off < 16; off <<= 1)
                key = umax64(key, (unsigned long long)__shfl_xor((unsigned long long)key, off));
            if ((lane & 15) == 0) atomicMax(&rowKeys[grow], key);
        }
    }

    // ---- col argmax ----
#pragma unroll
    for (int fn = 0; fn < 4; ++fn) {
        int gcol = colBase + wc * 64 + fn * 16 + (lane & 15);
        unsigned long long key = 0ULL;
#pragma unroll
        for (int fm = 0; fm < 4; ++fm) {
#pragma unroll
            for (int r = 0; r < 4; ++r) {
                int grow = rowBase + wr * 64 + fm * 16 + (lane >> 4) * 4 + r;
                unsigned long long k2 =
                    ((unsigned long long)f2ord(acc[fm][fn][r]) << 32) | (unsigned)(~(unsigned)grow);
                key = umax64(key, k2);
            }
        }
        key = umax64(key, (unsigned long long)__shfl_xor((unsigned long long)key, 16));
        key = umax64(key, (unsigned long long)__shfl_xor((unsigned long long)key, 32));
        if ((lane >> 4) == 0) atomicMax(&colKeys[gcol], key);
    }
}

// ---------------------------------------------------------------------------
// Kernel 4: loss partials from reconstructed fp32 = (h+l).
// ---------------------------------------------------------------------------
__global__ __launch_bounds__(256) void loss_partial_kernel(
    const unsigned short* __restrict__ Ah, const unsigned short* __restrict__ Al,
    const unsigned short* __restrict__ Bh, const unsigned short* __restrict__ Bl,
    float* __restrict__ partials)
{
    const int wave = threadIdx.x >> 6, lane = threadIdx.x & 63;
    const int r0 = blockIdx.x * 256 + wave * 64;
    float acc = 0.f;
    for (int r = r0; r < r0 + 64; ++r) {
        size_t base = (size_t)r * D + lane * 4;
        ushort4 ah = *reinterpret_cast<const ushort4*>(&Ah[base]);
        ushort4 al = *reinterpret_cast<const ushort4*>(&Al[base]);
        ushort4 bh = *reinterpret_cast<const ushort4*>(&Bh[base]);
        ushort4 bl = *reinterpret_cast<const ushort4*>(&Bl[base]);
        float a0 = bf_f(ah.x) + bf_f(al.x), b0 = bf_f(bh.x) + bf_f(bl.x);
        float a1 = bf_f(ah.y) + bf_f(al.y), b1 = bf_f(bh.y) + bf_f(bl.y);
        float a2 = bf_f(ah.z) + bf_f(al.z), b2 = bf_f(bh.z) + bf_f(bl.z);
        float a3 = bf_f(ah.w) + bf_f(al.w), b3 = bf_f(bh.w) + bf_f(bl.w);
        acc += fmaf(a0, b0, fmaf(a1, b1, fmaf(a2, b2, a3 * b3)));
    }
#pragma unroll
    for (int off = 32; off > 0; off >>= 1) acc += __shfl_down(acc, off);
    if (lane == 0) partials[blockIdx.x * 4 + wave] = acc;
}

// ---------------------------------------------------------------------------
// Kernel 5: finalize.
// ---------------------------------------------------------------------------
static constexpr int LOSS_PARTS = 128;

__global__ __launch_bounds__(256) void finalize_kernel(
    const unsigned long long* __restrict__ rkx, const unsigned long long* __restrict__ ckx,
    const unsigned long long* __restrict__ rky, const unsigned long long* __restrict__ cky,
    const float* __restrict__ parts, float* __restrict__ out)
{
    __shared__ int cnt[4];
    const int t = threadIdx.x;
    if (t < 4) cnt[t] = 0;
    __syncthreads();
    int c0 = 0, c1 = 0, c2 = 0, c3 = 0;
    for (int i = t; i < N; i += 256) {
        c0 += ((~(unsigned)rkx[i]) == (unsigned)i);
        c1 += ((~(unsigned)ckx[i]) == (unsigned)i);
        c2 += ((~(unsigned)rky[i]) == (unsigned)i);
        c3 += ((~(unsigned)cky[i]) == (unsigned)i);
    }
    atomicAdd(&cnt[0], c0);
    atomicAdd(&cnt[1], c1);
    atomicAdd(&cnt[2], c2);
    atomicAdd(&cnt[3], c3);
    __syncthreads();
    if (t == 0) {
        double sx = 0.0, sy = 0.0;
        for (int i = 0; i < LOSS_PARTS; ++i) { sx += (double)parts[i]; sy += (double)parts[LOSS_PARTS + i]; }
        float invN = 1.0f / (float)N;
        out[0] = (float)(-0.5 * (sx + sy) / (double)N);
        out[1] = 0.5f * ((float)cnt[1] * invN) + (float)cnt[0] * invN;
        out[2] = 0.5f * ((float)cnt[3] * invN) + (float)cnt[2] * invN;
    }
}

// ---------------------------------------------------------------------------
extern "C" void kernel_launch(void* const* d_in, const int* in_sizes, int n_in,
                              void* d_out, int out_size, void* d_ws, size_t ws_size,
                              hipStream_t stream)
{
    (void)in_sizes; (void)n_in; (void)out_size; (void)ws_size;
    const float* x  = (const float*)d_in[0];
    const float* y  = (const float*)d_in[1];
    const float* W1 = (const float*)d_in[2];
    const float* b1 = (const float*)d_in[3];
    const float* W2 = (const float*)d_in[4];
    const float* b2 = (const float*)d_in[5];
    float* out = (float*)d_out;

    const size_t ND = (size_t)N * D;
    unsigned short* pxh = (unsigned short*)d_ws;   // 8 bf16 planes x 4 MB = 32 MB
    unsigned short* pxl = pxh + ND;
    unsigned short* pyh = pxl + ND;
    unsigned short* pyl = pyh + ND;
    unsigned short* xh  = pyl + ND;
    unsigned short* xl  = xh + ND;
    unsigned short* yh  = xl + ND;
    unsigned short* yl  = yh + ND;
    unsigned long long* keys = (unsigned long long*)(yl + ND);   // 256 KB
    unsigned long long* rkx = keys + 0 * N;
    unsigned long long* ckx = keys + 1 * N;
    unsigned long long* rky = keys + 2 * N;
    unsigned long long* cky = keys + 3 * N;
    float* parts = (float*)(keys + 4 * N);

    hipMemsetAsync(keys, 0, 4 * (size_t)N * sizeof(unsigned long long), stream);

    mlp_norm_kernel<<<N / MLP_ROWS, 256, 0, stream>>>(x, W1, b1, W2, b2, pxh, pxl);
    mlp_norm_kernel<<<N / MLP_ROWS, 256, 0, stream>>>(y, W1, b1, W2, b2, pyh, pyl);
    rownorm_kernel<<<N / 4, 256, 0, stream>>>(x, xh, xl);
    rownorm_kernel<<<N / 4, 256, 0, stream>>>(y, yh, yl);

    sim_argmax_mfma<<<4096, 256, 0, stream>>>(pxh, pxl, yh, yl, rkx, ckx);
    sim_argmax_mfma<<<4096, 256, 0, stream>>>(pyh, pyl, xh, xl, rky, cky);

    loss_partial_kernel<<<32, 256, 0, stream>>>(pxh, pxl, yh, yl, parts);
    loss_partial_kernel<<<32, 256, 0, stream>>>(pyh, pyl, xh, xl, parts + LOSS_PARTS);

    finalize_kernel<<<1, 256, 0, stream>>>(rkx, ckx, rky, cky, parts, out);
}

// Round 3
// 569.648 us; speedup vs baseline: 1.7428x; 1.2526x over previous
//
#include <hip/hip_runtime.h>

// SimSiam: N=8192, D=256, H=128, fp32 in/out.
// Sim matrices via split-fp32 bf16 MFMA (3-term). Operand planes stored in
// MFMA-tile format: granule16B(panel,kt,kq,m) = ((panel*8+kt)*4+kq)*128+m,
// granule holds A[row=panel*128+m][k=kt*32+kq*8 .. +8] as 8 bf16.
// Loss = mean(diag(sim)) extracted from diagonal blocks' accumulators.

static constexpr int N = 8192;
static constexpr int D = 256;
static constexpr int H = 128;

typedef __attribute__((ext_vector_type(8))) short s16x8;
typedef __attribute__((ext_vector_type(4))) float fp32x4;

__device__ __forceinline__ unsigned f2ord(float f) {
    unsigned u = __float_as_uint(f);
    return (u & 0x80000000u) ? ~u : (u | 0x80000000u);
}
__device__ __forceinline__ unsigned long long umax64(unsigned long long a, unsigned long long b) {
    return a > b ? a : b;
}
__device__ __forceinline__ unsigned short bf16_rtne(float f) {
    unsigned u = __float_as_uint(f);
    unsigned r = 0x7FFFu + ((u >> 16) & 1u);
    return (unsigned short)((u + r) >> 16);
}
__device__ __forceinline__ float bf_f(unsigned short h) {
    return __uint_as_float((unsigned)h << 16);
}
__device__ __forceinline__ void split_store(float f, unsigned short* h, unsigned short* l) {
    unsigned short hb = bf16_rtne(f);
    *h = hb;
    *l = bf16_rtne(f - bf_f(hb));
}
__device__ __forceinline__ void gload16(const unsigned short* g, void* lds) {
    __builtin_amdgcn_global_load_lds(
        (const __attribute__((address_space(1))) unsigned int*)g,
        (__attribute__((address_space(3))) unsigned int*)lds, 16, 0, 0);
}
// tile-format granule index (in 8-ushort units)
__device__ __forceinline__ size_t gidx(int panel, int kt, int kq, int m) {
    return (((size_t)(panel * 8 + kt) * 4 + kq) * 128 + m) * 8;
}

// ---------------------------------------------------------------------------
// Kernel 1: Pn = rownormalize(relu(V@W1+b1)@W2+b2) -> tile-format hi/lo planes.
// ---------------------------------------------------------------------------
static constexpr int MLP_ROWS = 32;

__global__ __launch_bounds__(256) void mlp_norm_kernel(
    const float* __restrict__ V, const float* __restrict__ W1, const float* __restrict__ b1,
    const float* __restrict__ W2, const float* __restrict__ b2,
    unsigned short* __restrict__ Ph, unsigned short* __restrict__ Pl)
{
    __shared__ float sV[MLP_ROWS][D + 4];
    __shared__ float sH[MLP_ROWS][H + 4];
    __shared__ float sNrm[MLP_ROWS];

    const int t = threadIdx.x;
    const int rowBase = blockIdx.x * MLP_ROWS;

    for (int i = t; i < MLP_ROWS * (D / 4); i += 256) {
        int r = i >> 6, c4 = i & 63;
        float4 v = *reinterpret_cast<const float4*>(&V[(size_t)(rowBase + r) * D + c4 * 4]);
        sV[r][c4 * 4 + 0] = v.x; sV[r][c4 * 4 + 1] = v.y;
        sV[r][c4 * 4 + 2] = v.z; sV[r][c4 * 4 + 3] = v.w;
    }
    __syncthreads();

    {   // H = relu(V@W1 + b1)
        const int c = t & (H - 1);
        const int r0 = (t >> 7) * 16;
        float acc[16];
#pragma unroll
        for (int i = 0; i < 16; ++i) acc[i] = 0.f;
        for (int k4 = 0; k4 < D / 4; ++k4) {
            float w0 = W1[(k4 * 4 + 0) * H + c];
            float w1 = W1[(k4 * 4 + 1) * H + c];
            float w2 = W1[(k4 * 4 + 2) * H + c];
            float w3 = W1[(k4 * 4 + 3) * H + c];
#pragma unroll
            for (int i = 0; i < 16; ++i) {
                float4 v = *reinterpret_cast<const float4*>(&sV[r0 + i][k4 * 4]);
                acc[i] = fmaf(v.w, w3, fmaf(v.z, w2, fmaf(v.y, w1, fmaf(v.x, w0, acc[i]))));
            }
        }
        float bb = b1[c];
#pragma unroll
        for (int i = 0; i < 16; ++i) {
            float h = acc[i] + bb;
            sH[r0 + i][c] = h > 0.f ? h : 0.f;
        }
    }
    __syncthreads();

    {   // P = H@W2 + b2 -> back into sV
        const int c = t;
        float acc[MLP_ROWS];
#pragma unroll
        for (int i = 0; i < MLP_ROWS; ++i) acc[i] = 0.f;
        for (int k4 = 0; k4 < H / 4; ++k4) {
            float w0 = W2[(k4 * 4 + 0) * D + c];
            float w1 = W2[(k4 * 4 + 1) * D + c];
            float w2 = W2[(k4 * 4 + 2) * D + c];
            float w3 = W2[(k4 * 4 + 3) * D + c];
#pragma unroll
            for (int i = 0; i < MLP_ROWS; ++i) {
                float4 v = *reinterpret_cast<const float4*>(&sH[i][k4 * 4]);
                acc[i] = fmaf(v.w, w3, fmaf(v.z, w2, fmaf(v.y, w1, fmaf(v.x, w0, acc[i]))));
            }
        }
        float bb = b2[c];
        __syncthreads();
#pragma unroll
        for (int i = 0; i < MLP_ROWS; ++i) sV[i][c] = acc[i] + bb;
    }
    __syncthreads();

    {   // row norms
        const int wave = t >> 6, lane = t & 63;
        for (int r = wave; r < MLP_ROWS; r += 4) {
            float s = 0.f;
#pragma unroll
            for (int c = 0; c < D / 64; ++c) {
                float v = sV[r][lane + c * 64];
                s = fmaf(v, v, s);
            }
#pragma unroll
            for (int off = 32; off > 0; off >>= 1) s += __shfl_down(s, off);
            if (lane == 0) sNrm[r] = s;
        }
    }
    __syncthreads();

    for (int i = t; i < MLP_ROWS * (D / 4); i += 256) {
        int r = i >> 6, c4 = i & 63;
        float scale = 1.0f / fmaxf(sqrtf(sNrm[r]), 1e-12f);
        ushort4 h, l;
        split_store(sV[r][c4 * 4 + 0] * scale, &h.x, &l.x);
        split_store(sV[r][c4 * 4 + 1] * scale, &h.y, &l.y);
        split_store(sV[r][c4 * 4 + 2] * scale, &h.z, &l.z);
        split_store(sV[r][c4 * 4 + 3] * scale, &h.w, &l.w);
        int grow = rowBase + r;
        size_t g = gidx(grow >> 7, c4 >> 3, (c4 >> 1) & 3, grow & 127) + (size_t)(c4 & 1) * 4;
        *reinterpret_cast<ushort4*>(&Ph[g]) = h;
        *reinterpret_cast<ushort4*>(&Pl[g]) = l;
    }
}

// ---------------------------------------------------------------------------
// Kernel 2: plain row L2-normalize -> tile-format hi/lo planes. Wave per row.
// ---------------------------------------------------------------------------
__global__ __launch_bounds__(256) void rownorm_kernel(
    const float* __restrict__ V, unsigned short* __restrict__ Vh, unsigned short* __restrict__ Vl)
{
    const int wave = threadIdx.x >> 6, lane = threadIdx.x & 63;
    const int row = blockIdx.x * 4 + wave;
    float4 v = *reinterpret_cast<const float4*>(&V[(size_t)row * D + lane * 4]);
    float s = fmaf(v.x, v.x, fmaf(v.y, v.y, fmaf(v.z, v.z, v.w * v.w)));
#pragma unroll
    for (int off = 32; off > 0; off >>= 1) s += __shfl_down(s, off);
    s = __shfl(s, 0);
    float scale = 1.0f / fmaxf(sqrtf(s), 1e-12f);
    ushort4 h, l;
    split_store(v.x * scale, &h.x, &l.x);
    split_store(v.y * scale, &h.y, &l.y);
    split_store(v.z * scale, &h.z, &l.z);
    split_store(v.w * scale, &h.w, &l.w);
    size_t g = gidx(row >> 7, lane >> 3, (lane >> 1) & 3, row & 127) + (size_t)(lane & 1) * 4;
    *reinterpret_cast<ushort4*>(&Vh[g]) = h;
    *reinterpret_cast<ushort4*>(&Vl[g]) = l;
}

// ---------------------------------------------------------------------------
// Kernel 3: sim = (Ah+Al)@(Bh+Bl)^T via 3-term bf16 MFMA, streaming argmax +
// diagonal (loss) extraction. 128x128 tile, 4 waves, BK=32, virtual K = 768.
// ---------------------------------------------------------------------------
__global__ __launch_bounds__(256) void sim_argmax_mfma(
    const unsigned short* __restrict__ Ah, const unsigned short* __restrict__ Al,
    const unsigned short* __restrict__ Bh, const unsigned short* __restrict__ Bl,
    unsigned long long* __restrict__ rowKeys, unsigned long long* __restrict__ colKeys,
    float* __restrict__ diagParts)
{
    __shared__ s16x8 sA[2][512];   // 16 KB
    __shared__ s16x8 sB[2][512];   // 16 KB
    __shared__ float sDiag[4];

    const int t = threadIdx.x;
    const int w = t >> 6, lane = t & 63;
    const int wr = w >> 1, wc = w & 1;

    // bijective XCD swizzle: 4096 blocks, 8 XCDs, 512 per XCD
    int bid = blockIdx.x;
    int swz = (bid & 7) * 512 + (bid >> 3);
    const int panelA = swz & 63;    // fast -> A streams, B panel L2-resident
    const int panelB = swz >> 6;
    const int rowBase = panelA * 128;
    const int colBase = panelB * 128;

    fp32x4 acc[4][4];
#pragma unroll
    for (int i = 0; i < 4; ++i)
#pragma unroll
        for (int j = 0; j < 4; ++j) acc[i][j] = (fp32x4){0.f, 0.f, 0.f, 0.f};

    // stage one K-tile: contiguous 8KB per matrix; wave w loads chunks {w, w+4}
#define STAGE(buf, Ap, Bp, kt)                                                                     \
    do {                                                                                           \
        const size_t aB = (size_t)(panelA * 8 + (kt)) * 512;                                       \
        const size_t bB = (size_t)(panelB * 8 + (kt)) * 512;                                       \
        const int i0 = w, i1 = w + 4;                                                              \
        gload16((Ap) + (aB + i0 * 64 + lane) * 8, (void*)&sA[buf][i0 * 64]);                       \
        gload16((Ap) + (aB + i1 * 64 + lane) * 8, (void*)&sA[buf][i1 * 64]);                       \
        gload16((Bp) + (bB + i0 * 64 + lane) * 8, (void*)&sB[buf][i0 * 64]);                       \
        gload16((Bp) + (bB + i1 * 64 + lane) * 8, (void*)&sB[buf][i1 * 64]);                       \
    } while (0)

    STAGE(0, Ah, Bh, 0);

    const int gk = (lane >> 4) * 128 + (lane & 15);   // fragment slot base

    for (int vt = 0; vt < 24; ++vt) {
        const int cur = vt & 1;
        __syncthreads();   // staging of buf[cur] done; prior reads of buf[cur^1] done
        if (vt < 23) {
            int v2 = vt + 1;
            int p2 = v2 >> 3;
            int kt2 = v2 & 7;
            const unsigned short* Ap2 = (p2 == 1) ? Al : Ah;
            const unsigned short* Bp2 = (p2 == 2) ? Bl : Bh;
            STAGE(cur ^ 1, Ap2, Bp2, kt2);
        }
        s16x8 af[4], bf[4];
#pragma unroll
        for (int fm = 0; fm < 4; ++fm) af[fm] = sA[cur][gk + wr * 64 + fm * 16];
#pragma unroll
        for (int fn = 0; fn < 4; ++fn) bf[fn] = sB[cur][gk + wc * 64 + fn * 16];
#pragma unroll
        for (int fm = 0; fm < 4; ++fm)
#pragma unroll
            for (int fn = 0; fn < 4; ++fn)
                acc[fm][fn] = __builtin_amdgcn_mfma_f32_16x16x32_bf16(af[fm], bf[fn], acc[fm][fn], 0, 0, 0);
    }
#undef STAGE

    // ---- diagonal (loss) partial: only diagonal blocks ----
    if (panelA == panelB) {
        float s = 0.f;
        if (wr == wc) {
            int dr = (lane & 15) - (lane >> 4) * 4;
            if (dr >= 0 && dr < 4) {
#pragma unroll
                for (int fm = 0; fm < 4; ++fm) s += acc[fm][fm][dr];
            }
        }
#pragma unroll
        for (int off = 32; off > 0; off >>= 1) s += __shfl_down(s, off);
        if (lane == 0) sDiag[w] = s;
        __syncthreads();
        if (t == 0) diagParts[panelA] = ((sDiag[0] + sDiag[1]) + sDiag[2]) + sDiag[3];
    }

    // ---- row argmax: C/D map col=lane&15, row=(lane>>4)*4+r (m89/m91) ----
#pragma unroll
    for (int fm = 0; fm < 4; ++fm) {
#pragma unroll
        for (int r = 0; r < 4; ++r) {
            int grow = rowBase + wr * 64 + fm * 16 + (lane >> 4) * 4 + r;
            unsigned long long key = 0ULL;
#pragma unroll
            for (int fn = 0; fn < 4; ++fn) {
                int gcol = colBase + wc * 64 + fn * 16 + (lane & 15);
                unsigned long long k2 =
                    ((unsigned long long)f2ord(acc[fm][fn][r]) << 32) | (unsigned)(~(unsigned)gcol);
                key = umax64(key, k2);
            }
#pragma unroll
            for (int off = 1; off < 16; off <<= 1)
                key = umax64(key, (unsigned long long)__shfl_xor((unsigned long long)key, off));
            if ((lane & 15) == 0) atomicMax(&rowKeys[grow], key);
        }
    }

    // ---- col argmax ----
#pragma unroll
    for (int fn = 0; fn < 4; ++fn) {
        int gcol = colBase + wc * 64 + fn * 16 + (lane & 15);
        unsigned long long key = 0ULL;
#pragma unroll
        for (int fm = 0; fm < 4; ++fm) {
#pragma unroll
            for (int r = 0; r < 4; ++r) {
                int grow = rowBase + wr * 64 + fm * 16 + (lane >> 4) * 4 + r;
                unsigned long long k2 =
                    ((unsigned long long)f2ord(acc[fm][fn][r]) << 32) | (unsigned)(~(unsigned)grow);
                key = umax64(key, k2);
            }
        }
        key = umax64(key, (unsigned long long)__shfl_xor((unsigned long long)key, 16));
        key = umax64(key, (unsigned long long)__shfl_xor((unsigned long long)key, 32));
        if ((lane >> 4) == 0) atomicMax(&colKeys[gcol], key);
    }
}

// ---------------------------------------------------------------------------
// Kernel 4: finalize — deterministic counts + loss from diag partials.
// ---------------------------------------------------------------------------
__global__ __launch_bounds__(256) void finalize_kernel(
    const unsigned long long* __restrict__ rkx, const unsigned long long* __restrict__ ckx,
    const unsigned long long* __restrict__ rky, const unsigned long long* __restrict__ cky,
    const float* __restrict__ diagParts, float* __restrict__ out)
{
    __shared__ int cnt[4];
    const int t = threadIdx.x;
    if (t < 4) cnt[t] = 0;
    __syncthreads();
    int c0 = 0, c1 = 0, c2 = 0, c3 = 0;
    for (int i = t; i < N; i += 256) {
        c0 += ((~(unsigned)rkx[i]) == (unsigned)i);
        c1 += ((~(unsigned)ckx[i]) == (unsigned)i);
        c2 += ((~(unsigned)rky[i]) == (unsigned)i);
        c3 += ((~(unsigned)cky[i]) == (unsigned)i);
    }
    atomicAdd(&cnt[0], c0);
    atomicAdd(&cnt[1], c1);
    atomicAdd(&cnt[2], c2);
    atomicAdd(&cnt[3], c3);
    __syncthreads();
    if (t == 0) {
        double sx = 0.0, sy = 0.0;
        for (int i = 0; i < 64; ++i) { sx += (double)diagParts[i]; sy += (double)diagParts[64 + i]; }
        float invN = 1.0f / (float)N;
        out[0] = (float)(-0.5 * (sx + sy) / (double)N);
        out[1] = 0.5f * ((float)cnt[1] * invN) + (float)cnt[0] * invN;
        out[2] = 0.5f * ((float)cnt[3] * invN) + (float)cnt[2] * invN;
    }
}

// ---------------------------------------------------------------------------
extern "C" void kernel_launch(void* const* d_in, const int* in_sizes, int n_in,
                              void* d_out, int out_size, void* d_ws, size_t ws_size,
                              hipStream_t stream)
{
    (void)in_sizes; (void)n_in; (void)out_size; (void)ws_size;
    const float* x  = (const float*)d_in[0];
    const float* y  = (const float*)d_in[1];
    const float* W1 = (const float*)d_in[2];
    const float* b1 = (const float*)d_in[3];
    const float* W2 = (const float*)d_in[4];
    const float* b2 = (const float*)d_in[5];
    float* out = (float*)d_out;

    const size_t ND = (size_t)N * D;
    unsigned short* pxh = (unsigned short*)d_ws;   // 8 bf16 planes x 4 MB = 32 MB
    unsigned short* pxl = pxh + ND;
    unsigned short* pyh = pxl + ND;
    unsigned short* pyl = pyh + ND;
    unsigned short* xh  = pyl + ND;
    unsigned short* xl  = xh + ND;
    unsigned short* yh  = xl + ND;
    unsigned short* yl  = yh + ND;
    unsigned long long* keys = (unsigned long long*)(yl + ND);   // 256 KB
    unsigned long long* rkx = keys + 0 * N;
    unsigned long long* ckx = keys + 1 * N;
    unsigned long long* rky = keys + 2 * N;
    unsigned long long* cky = keys + 3 * N;
    float* diagParts = (float*)(keys + 4 * N);     // 128 floats

    hipMemsetAsync(keys, 0, 4 * (size_t)N * sizeof(unsigned long long), stream);

    mlp_norm_kernel<<<N / MLP_ROWS, 256, 0, stream>>>(x, W1, b1, W2, b2, pxh, pxl);
    mlp_norm_kernel<<<N / MLP_ROWS, 256, 0, stream>>>(y, W1, b1, W2, b2, pyh, pyl);
    rownorm_kernel<<<N / 4, 256, 0, stream>>>(x, xh, xl);
    rownorm_kernel<<<N / 4, 256, 0, stream>>>(y, yh, yl);

    sim_argmax_mfma<<<4096, 256, 0, stream>>>(pxh, pxl, yh, yl, rkx, ckx, diagParts);
    sim_argmax_mfma<<<4096, 256, 0, stream>>>(pyh, pyl, xh, xl, rky, cky, diagParts + 64);

    finalize_kernel<<<1, 256, 0, stream>>>(rkx, ckx, rky, cky, diagParts, out);
}

// Round 4
// 431.476 us; speedup vs baseline: 2.3009x; 1.3202x over previous
//
#include <hip/hip_runtime.h>

// SimSiam: N=8192, D=256, H=128, fp32 in/out.
// Sim matrices via split-fp32 bf16 MFMA (3-term), counted-vmcnt depth-4
// pipeline (no full drain in K-loop). Operand planes stored in MFMA-tile
// format: granule16B(panel,kt,kq,m) = ((panel*8+kt)*4+kq)*128+m.
// Loss = mean(diag(sim)) from diagonal blocks' accumulators.

static constexpr int N = 8192;
static constexpr int D = 256;
static constexpr int H = 128;

typedef __attribute__((ext_vector_type(8))) short s16x8;
typedef __attribute__((ext_vector_type(4))) float fp32x4;

__device__ __forceinline__ unsigned f2ord(float f) {
    unsigned u = __float_as_uint(f);
    return (u & 0x80000000u) ? ~u : (u | 0x80000000u);
}
__device__ __forceinline__ unsigned short bf16_rtne(float f) {
    unsigned u = __float_as_uint(f);
    unsigned r = 0x7FFFu + ((u >> 16) & 1u);
    return (unsigned short)((u + r) >> 16);
}
__device__ __forceinline__ float bf_f(unsigned short h) {
    return __uint_as_float((unsigned)h << 16);
}
__device__ __forceinline__ void split_store(float f, unsigned short* h, unsigned short* l) {
    unsigned short hb = bf16_rtne(f);
    *h = hb;
    *l = bf16_rtne(f - bf_f(hb));
}
__device__ __forceinline__ void gload16(const unsigned short* g, void* lds) {
    __builtin_amdgcn_global_load_lds(
        (const __attribute__((address_space(1))) unsigned int*)g,
        (__attribute__((address_space(3))) unsigned int*)lds, 16, 0, 0);
}
// tile-format granule index (in 8-ushort units)
__device__ __forceinline__ size_t gidx(int panel, int kt, int kq, int m) {
    return (((size_t)(panel * 8 + kt) * 4 + kq) * 128 + m) * 8;
}

// ---------------------------------------------------------------------------
// Kernel 1 (fused prep):
//   blocks [0,512):   MLP+rownorm -> tile-format hi/lo planes (x then y)
//   blocks [512,768): key zeroing + plain rownorm of x,y (64 rows/block)
// ---------------------------------------------------------------------------
static constexpr int MLP_ROWS = 32;

__global__ __launch_bounds__(256) void prep_kernel(
    const float* __restrict__ x, const float* __restrict__ y,
    const float* __restrict__ W1, const float* __restrict__ b1,
    const float* __restrict__ W2, const float* __restrict__ b2,
    unsigned short* __restrict__ pxh, unsigned short* __restrict__ pxl,
    unsigned short* __restrict__ pyh, unsigned short* __restrict__ pyl,
    unsigned short* __restrict__ xh, unsigned short* __restrict__ xl,
    unsigned short* __restrict__ yh, unsigned short* __restrict__ yl,
    unsigned long long* __restrict__ keys)
{
    const int bid = blockIdx.x;
    const int t = threadIdx.x;

    if (bid < 512) {
        // ---------------- MLP branch ----------------
        __shared__ float sV[MLP_ROWS][D + 4];
        __shared__ float sH[MLP_ROWS][H + 4];
        __shared__ float sNrm[MLP_ROWS];

        const float* V = (bid < 256) ? x : y;
        unsigned short* Ph = (bid < 256) ? pxh : pyh;
        unsigned short* Pl = (bid < 256) ? pxl : pyl;
        const int rowBase = (bid & 255) * MLP_ROWS;

        for (int i = t; i < MLP_ROWS * (D / 4); i += 256) {
            int r = i >> 6, c4 = i & 63;
            float4 v = *reinterpret_cast<const float4*>(&V[(size_t)(rowBase + r) * D + c4 * 4]);
            sV[r][c4 * 4 + 0] = v.x; sV[r][c4 * 4 + 1] = v.y;
            sV[r][c4 * 4 + 2] = v.z; sV[r][c4 * 4 + 3] = v.w;
        }
        __syncthreads();

        {   // H = relu(V@W1 + b1)
            const int c = t & (H - 1);
            const int r0 = (t >> 7) * 16;
            float acc[16];
#pragma unroll
            for (int i = 0; i < 16; ++i) acc[i] = 0.f;
            for (int k4 = 0; k4 < D / 4; ++k4) {
                float w0 = W1[(k4 * 4 + 0) * H + c];
                float w1 = W1[(k4 * 4 + 1) * H + c];
                float w2 = W1[(k4 * 4 + 2) * H + c];
                float w3 = W1[(k4 * 4 + 3) * H + c];
#pragma unroll
                for (int i = 0; i < 16; ++i) {
                    float4 v = *reinterpret_cast<const float4*>(&sV[r0 + i][k4 * 4]);
                    acc[i] = fmaf(v.w, w3, fmaf(v.z, w2, fmaf(v.y, w1, fmaf(v.x, w0, acc[i]))));
                }
            }
            float bb = b1[c];
#pragma unroll
            for (int i = 0; i < 16; ++i) {
                float h = acc[i] + bb;
                sH[r0 + i][c] = h > 0.f ? h : 0.f;
            }
        }
        __syncthreads();

        {   // P = H@W2 + b2 -> back into sV
            const int c = t;
            float acc[MLP_ROWS];
#pragma unroll
            for (int i = 0; i < MLP_ROWS; ++i) acc[i] = 0.f;
            for (int k4 = 0; k4 < H / 4; ++k4) {
                float w0 = W2[(k4 * 4 + 0) * D + c];
                float w1 = W2[(k4 * 4 + 1) * D + c];
                float w2 = W2[(k4 * 4 + 2) * D + c];
                float w3 = W2[(k4 * 4 + 3) * D + c];
#pragma unroll
                for (int i = 0; i < MLP_ROWS; ++i) {
                    float4 v = *reinterpret_cast<const float4*>(&sH[i][k4 * 4]);
                    acc[i] = fmaf(v.w, w3, fmaf(v.z, w2, fmaf(v.y, w1, fmaf(v.x, w0, acc[i]))));
                }
            }
            float bb = b2[c];
            __syncthreads();
#pragma unroll
            for (int i = 0; i < MLP_ROWS; ++i) sV[i][c] = acc[i] + bb;
        }
        __syncthreads();

        {   // row norms
            const int wave = t >> 6, lane = t & 63;
            for (int r = wave; r < MLP_ROWS; r += 4) {
                float s = 0.f;
#pragma unroll
                for (int c = 0; c < D / 64; ++c) {
                    float v = sV[r][lane + c * 64];
                    s = fmaf(v, v, s);
                }
#pragma unroll
                for (int off = 32; off > 0; off >>= 1) s += __shfl_down(s, off);
                if (lane == 0) sNrm[r] = s;
            }
        }
        __syncthreads();

        for (int i = t; i < MLP_ROWS * (D / 4); i += 256) {
            int r = i >> 6, c4 = i & 63;
            float scale = 1.0f / fmaxf(sqrtf(sNrm[r]), 1e-12f);
            ushort4 h, l;
            split_store(sV[r][c4 * 4 + 0] * scale, &h.x, &l.x);
            split_store(sV[r][c4 * 4 + 1] * scale, &h.y, &l.y);
            split_store(sV[r][c4 * 4 + 2] * scale, &h.z, &l.z);
            split_store(sV[r][c4 * 4 + 3] * scale, &h.w, &l.w);
            int grow = rowBase + r;
            size_t g = gidx(grow >> 7, c4 >> 3, (c4 >> 1) & 3, grow & 127) + (size_t)(c4 & 1) * 4;
            *reinterpret_cast<ushort4*>(&Ph[g]) = h;
            *reinterpret_cast<ushort4*>(&Pl[g]) = l;
        }
    } else {
        // ---------------- rownorm + key-zero branch ----------------
        const int rb = bid - 512;               // 0..255
        if (t < 128) keys[rb * 128 + t] = 0ULL; // zero 32768 keys total
        const int wave = t >> 6, lane = t & 63;
#pragma unroll 1
        for (int i = 0; i < 16; ++i) {
            int gr = rb * 64 + wave * 16 + i;    // 0..16383
            const float* V = (gr < N) ? x : y;
            unsigned short* Vh = (gr < N) ? xh : yh;
            unsigned short* Vl = (gr < N) ? xl : yl;
            int row = gr & (N - 1);
            float4 v = *reinterpret_cast<const float4*>(&V[(size_t)row * D + lane * 4]);
            float s = fmaf(v.x, v.x, fmaf(v.y, v.y, fmaf(v.z, v.z, v.w * v.w)));
#pragma unroll
            for (int off = 32; off > 0; off >>= 1) s += __shfl_down(s, off);
            s = __shfl(s, 0);
            float scale = 1.0f / fmaxf(sqrtf(s), 1e-12f);
            ushort4 h, l;
            split_store(v.x * scale, &h.x, &l.x);
            split_store(v.y * scale, &h.y, &l.y);
            split_store(v.z * scale, &h.z, &l.z);
            split_store(v.w * scale, &h.w, &l.w);
            size_t g = gidx(row >> 7, lane >> 3, (lane >> 1) & 3, row & 127) + (size_t)(lane & 1) * 4;
            *reinterpret_cast<ushort4*>(&Vh[g]) = h;
            *reinterpret_cast<ushort4*>(&Vl[g]) = l;
        }
    }
}

// ---------------------------------------------------------------------------
// Kernel 2: sim = (Ah+Al)@(Bh+Bl)^T via 3-term bf16 MFMA, depth-4 counted
// vmcnt pipeline, streaming argmax + diagonal extraction.
// 128x128 tile, 4 waves, BK=32, virtual K = 768 (24 tiles).
// ---------------------------------------------------------------------------
__global__ __launch_bounds__(256) void sim_argmax_mfma(
    const unsigned short* __restrict__ Ah, const unsigned short* __restrict__ Al,
    const unsigned short* __restrict__ Bh, const unsigned short* __restrict__ Bl,
    unsigned long long* __restrict__ rowKeys, unsigned long long* __restrict__ colKeys,
    float* __restrict__ diagParts)
{
    __shared__ s16x8 sA[4][512];   // 32 KB (4-deep ring)
    __shared__ s16x8 sB[4][512];   // 32 KB
    __shared__ float sDiag[4];

    const int t = threadIdx.x;
    const int w = t >> 6, lane = t & 63;
    const int wr = w >> 1, wc = w & 1;

    // bijective XCD swizzle: 4096 blocks, 8 XCDs, 512 per XCD
    int bid = blockIdx.x;
    int swz = (bid & 7) * 512 + (bid >> 3);
    const int panelA = swz & 63;    // fast -> A streams, B panel L2-resident
    const int panelB = swz >> 6;
    const int rowBase = panelA * 128;
    const int colBase = panelB * 128;

    fp32x4 acc[4][4];
#pragma unroll
    for (int i = 0; i < 4; ++i)
#pragma unroll
        for (int j = 0; j < 4; ++j) acc[i][j] = (fp32x4){0.f, 0.f, 0.f, 0.f};

    // stage tile v into ring slot v&3 (4 gload instrs/wave -> vmcnt +4/tile)
#define STAGE(v)                                                                                   \
    do {                                                                                           \
        const int p2 = (v) >> 3, kt2 = (v) & 7;                                                    \
        const unsigned short* Ap = (p2 == 1) ? Al : Ah;                                            \
        const unsigned short* Bp = (p2 == 2) ? Bl : Bh;                                            \
        const int bf_ = (v) & 3;                                                                   \
        const size_t aB = (size_t)(panelA * 8 + kt2) * 512;                                        \
        const size_t bB = (size_t)(panelB * 8 + kt2) * 512;                                        \
        const int i0 = w, i1 = w + 4;                                                              \
        gload16(Ap + (aB + i0 * 64 + lane) * 8, (void*)&sA[bf_][i0 * 64]);                         \
        gload16(Ap + (aB + i1 * 64 + lane) * 8, (void*)&sA[bf_][i1 * 64]);                         \
        gload16(Bp + (bB + i0 * 64 + lane) * 8, (void*)&sB[bf_][i0 * 64]);                         \
        gload16(Bp + (bB + i1 * 64 + lane) * 8, (void*)&sB[bf_][i1 * 64]);                         \
    } while (0)

    STAGE(0);
    STAGE(1);
    STAGE(2);

    const int gk = (lane >> 4) * 128 + (lane & 15);   // fragment slot base
    const int akBase = gk + wr * 64;
    const int bkBase = gk + wc * 64;

#pragma unroll
    for (int v = 0; v < 24; ++v) {
        // derived wait: own-wave loads for tile v landed, up to 8 (2 tiles) in flight
        if (v <= 21) {
            asm volatile("s_waitcnt vmcnt(8)" ::: "memory");
        } else if (v == 22) {
            asm volatile("s_waitcnt vmcnt(4)" ::: "memory");
        } else {
            asm volatile("s_waitcnt vmcnt(0)" ::: "memory");
        }
        __builtin_amdgcn_s_barrier();      // all waves' tile-v loads landed
        __builtin_amdgcn_sched_barrier(0);
        if (v < 21) STAGE(v + 3);          // ring slot (v+3)&3 freed at step v-1
        const int cur = v & 3;
        s16x8 af[4], bfr[4];
#pragma unroll
        for (int fm = 0; fm < 4; ++fm) af[fm] = sA[cur][akBase + fm * 16];
#pragma unroll
        for (int fn = 0; fn < 4; ++fn) bfr[fn] = sB[cur][bkBase + fn * 16];
#pragma unroll
        for (int fm = 0; fm < 4; ++fm)
#pragma unroll
            for (int fn = 0; fn < 4; ++fn)
                acc[fm][fn] = __builtin_amdgcn_mfma_f32_16x16x32_bf16(af[fm], bfr[fn], acc[fm][fn], 0, 0, 0);
    }
#undef STAGE

    // ---- diagonal (loss) partial: only diagonal blocks ----
    if (panelA == panelB) {
        float s = 0.f;
        if (wr == wc) {
            int dr = (lane & 15) - (lane >> 4) * 4;
            if (dr >= 0 && dr < 4) {
#pragma unroll
                for (int fm = 0; fm < 4; ++fm) s += acc[fm][fm][dr];
            }
        }
#pragma unroll
        for (int off = 32; off > 0; off >>= 1) s += __shfl_down(s, off);
        if (lane == 0) sDiag[w] = s;
        __syncthreads();
        if (t == 0) diagParts[panelA] = ((sDiag[0] + sDiag[1]) + sDiag[2]) + sDiag[3];
    }

    // ---- row argmax (value-first): C/D map col=lane&15, row=(lane>>4)*4+r ----
#pragma unroll
    for (int fm = 0; fm < 4; ++fm) {
#pragma unroll
        for (int r = 0; r < 4; ++r) {
            int grow = rowBase + wr * 64 + fm * 16 + (lane >> 4) * 4 + r;
            float m = fmaxf(fmaxf(acc[fm][0][r], acc[fm][1][r]), fmaxf(acc[fm][2][r], acc[fm][3][r]));
#pragma unroll
            for (int off = 1; off < 16; off <<= 1) m = fmaxf(m, __shfl_xor(m, off));
            unsigned idx = 0xFFFFFFFFu;
#pragma unroll
            for (int fn = 0; fn < 4; ++fn) {
                unsigned gcol = (unsigned)(colBase + wc * 64 + fn * 16 + (lane & 15));
                if (acc[fm][fn][r] == m && gcol < idx) idx = gcol;
            }
#pragma unroll
            for (int off = 1; off < 16; off <<= 1) {
                unsigned o = __shfl_xor(idx, off);
                if (o < idx) idx = o;
            }
            if ((lane & 15) == 0)
                atomicMax(&rowKeys[grow], ((unsigned long long)f2ord(m) << 32) | (unsigned)(~idx));
        }
    }

    // ---- col argmax (value-first) ----
#pragma unroll
    for (int fn = 0; fn < 4; ++fn) {
        int gcol = colBase + wc * 64 + fn * 16 + (lane & 15);
        float m = -3.4e38f;
#pragma unroll
        for (int fm = 0; fm < 4; ++fm) {
            float m01 = fmaxf(acc[fm][fn][0], acc[fm][fn][1]);
            float m23 = fmaxf(acc[fm][fn][2], acc[fm][fn][3]);
            m = fmaxf(m, fmaxf(m01, m23));
        }
        m = fmaxf(m, __shfl_xor(m, 16));
        m = fmaxf(m, __shfl_xor(m, 32));
        unsigned idx = 0xFFFFFFFFu;
#pragma unroll
        for (int fm = 0; fm < 4; ++fm) {
#pragma unroll
            for (int r = 0; r < 4; ++r) {
                unsigned grow = (unsigned)(rowBase + wr * 64 + fm * 16 + (lane >> 4) * 4 + r);
                if (acc[fm][fn][r] == m && grow < idx) idx = grow;
            }
        }
        {
            unsigned o = __shfl_xor(idx, 16);
            if (o < idx) idx = o;
            o = __shfl_xor(idx, 32);
            if (o < idx) idx = o;
        }
        if ((lane >> 4) == 0)
            atomicMax(&colKeys[gcol], ((unsigned long long)f2ord(m) << 32) | (unsigned)(~idx));
    }
}

// ---------------------------------------------------------------------------
// Kernel 3: finalize — deterministic counts + loss from diag partials.
// ---------------------------------------------------------------------------
__global__ __launch_bounds__(256) void finalize_kernel(
    const unsigned long long* __restrict__ rkx, const unsigned long long* __restrict__ ckx,
    const unsigned long long* __restrict__ rky, const unsigned long long* __restrict__ cky,
    const float* __restrict__ diagParts, float* __restrict__ out)
{
    __shared__ int cnt[4];
    const int t = threadIdx.x;
    if (t < 4) cnt[t] = 0;
    __syncthreads();
    int c0 = 0, c1 = 0, c2 = 0, c3 = 0;
    for (int i = t; i < N; i += 256) {
        c0 += ((~(unsigned)rkx[i]) == (unsigned)i);
        c1 += ((~(unsigned)ckx[i]) == (unsigned)i);
        c2 += ((~(unsigned)rky[i]) == (unsigned)i);
        c3 += ((~(unsigned)cky[i]) == (unsigned)i);
    }
    atomicAdd(&cnt[0], c0);
    atomicAdd(&cnt[1], c1);
    atomicAdd(&cnt[2], c2);
    atomicAdd(&cnt[3], c3);
    __syncthreads();
    if (t == 0) {
        double sx = 0.0, sy = 0.0;
        for (int i = 0; i < 64; ++i) { sx += (double)diagParts[i]; sy += (double)diagParts[64 + i]; }
        float invN = 1.0f / (float)N;
        out[0] = (float)(-0.5 * (sx + sy) / (double)N);
        out[1] = 0.5f * ((float)cnt[1] * invN) + (float)cnt[0] * invN;
        out[2] = 0.5f * ((float)cnt[3] * invN) + (float)cnt[2] * invN;
    }
}

// ---------------------------------------------------------------------------
extern "C" void kernel_launch(void* const* d_in, const int* in_sizes, int n_in,
                              void* d_out, int out_size, void* d_ws, size_t ws_size,
                              hipStream_t stream)
{
    (void)in_sizes; (void)n_in; (void)out_size; (void)ws_size;
    const float* x  = (const float*)d_in[0];
    const float* y  = (const float*)d_in[1];
    const float* W1 = (const float*)d_in[2];
    const float* b1 = (const float*)d_in[3];
    const float* W2 = (const float*)d_in[4];
    const float* b2 = (const float*)d_in[5];
    float* out = (float*)d_out;

    const size_t ND = (size_t)N * D;
    unsigned short* pxh = (unsigned short*)d_ws;   // 8 bf16 planes x 4 MB = 32 MB
    unsigned short* pxl = pxh + ND;
    unsigned short* pyh = pxl + ND;
    unsigned short* pyl = pyh + ND;
    unsigned short* xh  = pyl + ND;
    unsigned short* xl  = xh + ND;
    unsigned short* yh  = xl + ND;
    unsigned short* yl  = yh + ND;
    unsigned long long* keys = (unsigned long long*)(yl + ND);   // 256 KB
    unsigned long long* rkx = keys + 0 * N;
    unsigned long long* ckx = keys + 1 * N;
    unsigned long long* rky = keys + 2 * N;
    unsigned long long* cky = keys + 3 * N;
    float* diagParts = (float*)(keys + 4 * N);     // 128 floats

    prep_kernel<<<768, 256, 0, stream>>>(x, y, W1, b1, W2, b2,
                                         pxh, pxl, pyh, pyl, xh, xl, yh, yl, keys);

    sim_argmax_mfma<<<4096, 256, 0, stream>>>(pxh, pxl, yh, yl, rkx, ckx, diagParts);
    sim_argmax_mfma<<<4096, 256, 0, stream>>>(pyh, pyl, xh, xl, rky, cky, diagParts + 64);

    finalize_kernel<<<1, 256, 0, stream>>>(rkx, ckx, rky, cky, diagParts, out);
}

// Round 5
// 380.278 us; speedup vs baseline: 2.6106x; 1.1346x over previous
//
#include <hip/hip_runtime.h>

// SimSiam: N=8192, D=256, H=128, fp32 in/out.
// Sim matrices via split-fp32 bf16 MFMA (3-term), 256x128 blocks, 8 waves,
// depth-3 LDS ring with counted vmcnt(3). Operand planes in MFMA-tile format:
// granule16B(panel,kt,kq,m) = ((panel*8+kt)*4+kq)*128+m  (panel = 128 rows).
// Loss = mean(diag(sim)) from diagonal blocks' accumulators.

static constexpr int N = 8192;
static constexpr int D = 256;
static constexpr int H = 128;

typedef __attribute__((ext_vector_type(8))) short s16x8;
typedef __attribute__((ext_vector_type(4))) float fp32x4;
typedef unsigned long long ull;

__device__ __forceinline__ unsigned f2ord(float f) {
    unsigned u = __float_as_uint(f);
    return (u & 0x80000000u) ? ~u : (u | 0x80000000u);
}
__device__ __forceinline__ unsigned short bf16_rtne(float f) {
    unsigned u = __float_as_uint(f);
    unsigned r = 0x7FFFu + ((u >> 16) & 1u);
    return (unsigned short)((u + r) >> 16);
}
__device__ __forceinline__ float bf_f(unsigned short h) {
    return __uint_as_float((unsigned)h << 16);
}
__device__ __forceinline__ void split_store(float f, unsigned short* h, unsigned short* l) {
    unsigned short hb = bf16_rtne(f);
    *h = hb;
    *l = bf16_rtne(f - bf_f(hb));
}
__device__ __forceinline__ void gload16(const unsigned short* g, void* lds) {
    __builtin_amdgcn_global_load_lds(
        (const __attribute__((address_space(1))) unsigned int*)g,
        (__attribute__((address_space(3))) unsigned int*)lds, 16, 0, 0);
}
// tile-format granule index (in ushort units)
__device__ __forceinline__ size_t gidx(int panel, int kt, int kq, int m) {
    return (((size_t)(panel * 8 + kt) * 4 + kq) * 128 + m) * 8;
}

// ---------------------------------------------------------------------------
// Kernel 1 (fused prep):
//   blocks [0,512):   MLP+rownorm -> tile-format hi/lo planes (x then y)
//   blocks [512,768): key zeroing + cnt zeroing + plain rownorm of x,y
// ---------------------------------------------------------------------------
static constexpr int MLP_ROWS = 32;

__global__ __launch_bounds__(256) void prep_kernel(
    const float* __restrict__ x, const float* __restrict__ y,
    const float* __restrict__ W1, const float* __restrict__ b1,
    const float* __restrict__ W2, const float* __restrict__ b2,
    unsigned short* __restrict__ pxh, unsigned short* __restrict__ pxl,
    unsigned short* __restrict__ pyh, unsigned short* __restrict__ pyl,
    unsigned short* __restrict__ xh, unsigned short* __restrict__ xl,
    unsigned short* __restrict__ yh, unsigned short* __restrict__ yl,
    ull* __restrict__ keys, int* __restrict__ cnt)
{
    const int bid = blockIdx.x;
    const int t = threadIdx.x;

    if (bid < 512) {
        // ---------------- MLP branch ----------------
        __shared__ float sV[MLP_ROWS][D + 4];
        __shared__ float sH[MLP_ROWS][H + 4];
        __shared__ float sNrm[MLP_ROWS];

        const float* V = (bid < 256) ? x : y;
        unsigned short* Ph = (bid < 256) ? pxh : pyh;
        unsigned short* Pl = (bid < 256) ? pxl : pyl;
        const int rowBase = (bid & 255) * MLP_ROWS;

        for (int i = t; i < MLP_ROWS * (D / 4); i += 256) {
            int r = i >> 6, c4 = i & 63;
            float4 v = *reinterpret_cast<const float4*>(&V[(size_t)(rowBase + r) * D + c4 * 4]);
            sV[r][c4 * 4 + 0] = v.x; sV[r][c4 * 4 + 1] = v.y;
            sV[r][c4 * 4 + 2] = v.z; sV[r][c4 * 4 + 3] = v.w;
        }
        __syncthreads();

        {   // H = relu(V@W1 + b1)
            const int c = t & (H - 1);
            const int r0 = (t >> 7) * 16;
            float acc[16];
#pragma unroll
            for (int i = 0; i < 16; ++i) acc[i] = 0.f;
            for (int k4 = 0; k4 < D / 4; ++k4) {
                float w0 = W1[(k4 * 4 + 0) * H + c];
                float w1 = W1[(k4 * 4 + 1) * H + c];
                float w2 = W1[(k4 * 4 + 2) * H + c];
                float w3 = W1[(k4 * 4 + 3) * H + c];
#pragma unroll
                for (int i = 0; i < 16; ++i) {
                    float4 v = *reinterpret_cast<const float4*>(&sV[r0 + i][k4 * 4]);
                    acc[i] = fmaf(v.w, w3, fmaf(v.z, w2, fmaf(v.y, w1, fmaf(v.x, w0, acc[i]))));
                }
            }
            float bb = b1[c];
#pragma unroll
            for (int i = 0; i < 16; ++i) {
                float h = acc[i] + bb;
                sH[r0 + i][c] = h > 0.f ? h : 0.f;
            }
        }
        __syncthreads();

        {   // P = H@W2 + b2 -> back into sV
            const int c = t;
            float acc[MLP_ROWS];
#pragma unroll
            for (int i = 0; i < MLP_ROWS; ++i) acc[i] = 0.f;
            for (int k4 = 0; k4 < H / 4; ++k4) {
                float w0 = W2[(k4 * 4 + 0) * D + c];
                float w1 = W2[(k4 * 4 + 1) * D + c];
                float w2 = W2[(k4 * 4 + 2) * D + c];
                float w3 = W2[(k4 * 4 + 3) * D + c];
#pragma unroll
                for (int i = 0; i < MLP_ROWS; ++i) {
                    float4 v = *reinterpret_cast<const float4*>(&sH[i][k4 * 4]);
                    acc[i] = fmaf(v.w, w3, fmaf(v.z, w2, fmaf(v.y, w1, fmaf(v.x, w0, acc[i]))));
                }
            }
            float bb = b2[c];
            __syncthreads();
#pragma unroll
            for (int i = 0; i < MLP_ROWS; ++i) sV[i][c] = acc[i] + bb;
        }
        __syncthreads();

        {   // row norms
            const int wave = t >> 6, lane = t & 63;
            for (int r = wave; r < MLP_ROWS; r += 4) {
                float s = 0.f;
#pragma unroll
                for (int c = 0; c < D / 64; ++c) {
                    float v = sV[r][lane + c * 64];
                    s = fmaf(v, v, s);
                }
#pragma unroll
                for (int off = 32; off > 0; off >>= 1) s += __shfl_down(s, off);
                if (lane == 0) sNrm[r] = s;
            }
        }
        __syncthreads();

        for (int i = t; i < MLP_ROWS * (D / 4); i += 256) {
            int r = i >> 6, c4 = i & 63;
            float scale = 1.0f / fmaxf(sqrtf(sNrm[r]), 1e-12f);
            ushort4 h, l;
            split_store(sV[r][c4 * 4 + 0] * scale, &h.x, &l.x);
            split_store(sV[r][c4 * 4 + 1] * scale, &h.y, &l.y);
            split_store(sV[r][c4 * 4 + 2] * scale, &h.z, &l.z);
            split_store(sV[r][c4 * 4 + 3] * scale, &h.w, &l.w);
            int grow = rowBase + r;
            size_t g = gidx(grow >> 7, c4 >> 3, (c4 >> 1) & 3, grow & 127) + (size_t)(c4 & 1) * 4;
            *reinterpret_cast<ushort4*>(&Ph[g]) = h;
            *reinterpret_cast<ushort4*>(&Pl[g]) = l;
        }
    } else {
        // ---------------- rownorm + zeroing branch ----------------
        const int rb = bid - 512;               // 0..255
        if (t < 128) keys[rb * 128 + t] = 0ULL; // zero 32768 keys total
        if (bid == 512 && t < 4) cnt[t] = 0;
        const int wave = t >> 6, lane = t & 63;
#pragma unroll 1
        for (int i = 0; i < 16; ++i) {
            int gr = rb * 64 + wave * 16 + i;    // 0..16383
            const float* V = (gr < N) ? x : y;
            unsigned short* Vh = (gr < N) ? xh : yh;
            unsigned short* Vl = (gr < N) ? xl : yl;
            int row = gr & (N - 1);
            float4 v = *reinterpret_cast<const float4*>(&V[(size_t)row * D + lane * 4]);
            float s = fmaf(v.x, v.x, fmaf(v.y, v.y, fmaf(v.z, v.z, v.w * v.w)));
#pragma unroll
            for (int off = 32; off > 0; off >>= 1) s += __shfl_down(s, off);
            s = __shfl(s, 0);
            float scale = 1.0f / fmaxf(sqrtf(s), 1e-12f);
            ushort4 h, l;
            split_store(v.x * scale, &h.x, &l.x);
            split_store(v.y * scale, &h.y, &l.y);
            split_store(v.z * scale, &h.z, &l.z);
            split_store(v.w * scale, &h.w, &l.w);
            size_t g = gidx(row >> 7, lane >> 3, (lane >> 1) & 3, row & 127) + (size_t)(lane & 1) * 4;
            *reinterpret_cast<ushort4*>(&Vh[g]) = h;
            *reinterpret_cast<ushort4*>(&Vl[g]) = l;
        }
    }
}

// ---------------------------------------------------------------------------
// Kernel 2: sim = (Ah+Al)@(Bh+Bl)^T, 3-term bf16 MFMA. 256x128 block, 8 waves
// (4x2 of 64x64), depth-3 ring, counted vmcnt(3). Virtual K = 768 (24 tiles).
// ---------------------------------------------------------------------------
__global__ __launch_bounds__(512, 4) void sim_argmax_mfma(
    const unsigned short* __restrict__ Ah, const unsigned short* __restrict__ Al,
    const unsigned short* __restrict__ Bh, const unsigned short* __restrict__ Bl,
    ull* __restrict__ rowKeys, ull* __restrict__ colKeys,
    float* __restrict__ diagParts)
{
    __shared__ s16x8 sA[3][1024];   // 48 KB: [half(2)][kq(4)][m(128)]
    __shared__ s16x8 sB[3][512];    // 24 KB: [kq(4)][m(128)]
    __shared__ float sDiag[8];

    const int t = threadIdx.x;
    const int w = t >> 6, lane = t & 63;
    const int wr = w >> 1, wc = w & 1;   // 4x2 wave grid, each 64x64

    // grid 2048 = 32 rowTiles x 64 colTiles; bijective XCD swizzle (8 x 256)
    const int bid = blockIdx.x;
    const int swz = (bid & 7) * 256 + (bid >> 3);
    const int rowTile = swz & 31;        // fast -> A streams, B chunk resident
    const int colTile = swz >> 5;
    const int rowBase = rowTile * 256;
    const int colBase = colTile * 128;
    const int panelA0 = rowTile * 2;

    fp32x4 acc[4][4];
#pragma unroll
    for (int i = 0; i < 4; ++i)
#pragma unroll
        for (int j = 0; j < 4; ++j) acc[i][j] = (fp32x4){0.f, 0.f, 0.f, 0.f};

    const int lg = w * 64 + lane;        // granule-in-round 0..511
    const unsigned short* bAh = Ah + (size_t)panelA0 * 32768 + (size_t)lg * 8;
    const unsigned short* bAl = Al + (size_t)panelA0 * 32768 + (size_t)lg * 8;
    const unsigned short* bBh = Bh + (size_t)colTile * 32768 + (size_t)lg * 8;
    const unsigned short* bBl = Bl + (size_t)colTile * 32768 + (size_t)lg * 8;

    // 3 gload16 per wave per tile: A panel0 (8KB), A panel1 (8KB), B (8KB)
#define STAGE(v)                                                                \
    do {                                                                        \
        const int kt_ = (v) & 7;                                                \
        const unsigned short* pa_ = (((v) >> 3) == 1) ? bAl : bAh;              \
        const unsigned short* pb_ = (((v) >> 3) == 2) ? bBl : bBh;              \
        const int sl_ = (v) % 3;                                                \
        gload16(pa_ + kt_ * 4096, (void*)&sA[sl_][w * 64]);                     \
        gload16(pa_ + kt_ * 4096 + 32768, (void*)&sA[sl_][512 + w * 64]);       \
        gload16(pb_ + kt_ * 4096, (void*)&sB[sl_][w * 64]);                     \
    } while (0)

    STAGE(0);
    STAGE(1);

    // fragment slot bases (conflict-free: 16 consecutive 16B granules/lane-group)
    const int aBase = (wr >> 1) * 512 + (lane >> 4) * 128 + (wr & 1) * 64 + (lane & 15);
    const int bBase = (lane >> 4) * 128 + wc * 64 + (lane & 15);

#pragma unroll
    for (int v = 0; v < 24; ++v) {
        if (v < 23) { asm volatile("s_waitcnt vmcnt(3)" ::: "memory"); }
        else        { asm volatile("s_waitcnt vmcnt(0)" ::: "memory"); }
        __builtin_amdgcn_sched_barrier(0);
        __builtin_amdgcn_s_barrier();
        __builtin_amdgcn_sched_barrier(0);
        if (v < 22) STAGE(v + 2);
        const int sl = v % 3;
        s16x8 af[4];
#pragma unroll
        for (int fm = 0; fm < 4; ++fm) af[fm] = sA[sl][aBase + fm * 16];
        {
            s16x8 b0 = sB[sl][bBase], b1 = sB[sl][bBase + 16];
            __builtin_amdgcn_s_setprio(1);
#pragma unroll
            for (int fm = 0; fm < 4; ++fm)
                acc[fm][0] = __builtin_amdgcn_mfma_f32_16x16x32_bf16(af[fm], b0, acc[fm][0], 0, 0, 0);
#pragma unroll
            for (int fm = 0; fm < 4; ++fm)
                acc[fm][1] = __builtin_amdgcn_mfma_f32_16x16x32_bf16(af[fm], b1, acc[fm][1], 0, 0, 0);
            __builtin_amdgcn_s_setprio(0);
        }
        {
            s16x8 b2 = sB[sl][bBase + 32], b3 = sB[sl][bBase + 48];
            __builtin_amdgcn_s_setprio(1);
#pragma unroll
            for (int fm = 0; fm < 4; ++fm)
                acc[fm][2] = __builtin_amdgcn_mfma_f32_16x16x32_bf16(af[fm], b2, acc[fm][2], 0, 0, 0);
#pragma unroll
            for (int fm = 0; fm < 4; ++fm)
                acc[fm][3] = __builtin_amdgcn_mfma_f32_16x16x32_bf16(af[fm], b3, acc[fm][3], 0, 0, 0);
            __builtin_amdgcn_s_setprio(0);
        }
    }
#undef STAGE

    const int R0 = rowBase + wr * 64;
    const int C0 = colBase + wc * 64;

    // ---- diagonal (loss) partial ----
    if (rowTile == (colTile >> 1)) {            // block-uniform
        float s = 0.f;
        if (wr == 2 * (colTile & 1) + wc) {     // wave's 64x64 sits on diagonal
            int dr = (lane & 15) - (lane >> 4) * 4;
            if (dr >= 0 && dr < 4) {
#pragma unroll
                for (int fm = 0; fm < 4; ++fm) s += acc[fm][fm][dr];
            }
        }
#pragma unroll
        for (int off = 32; off > 0; off >>= 1) s += __shfl_down(s, off);
        if (lane == 0) sDiag[w] = s;
        __syncthreads();
        if (t == 0) {
            float d = 0.f;
#pragma unroll
            for (int i = 0; i < 8; ++i) d += sDiag[i];
            diagParts[colTile] = d;
        }
    }

    // ---- row argmax (value-first): C/D map col=lane&15, row=(lane>>4)*4+r ----
#pragma unroll
    for (int fm = 0; fm < 4; ++fm) {
#pragma unroll
        for (int r = 0; r < 4; ++r) {
            int grow = R0 + fm * 16 + (lane >> 4) * 4 + r;
            float m = fmaxf(fmaxf(acc[fm][0][r], acc[fm][1][r]), fmaxf(acc[fm][2][r], acc[fm][3][r]));
#pragma unroll
            for (int off = 1; off < 16; off <<= 1) m = fmaxf(m, __shfl_xor(m, off));
            unsigned idx = 0xFFFFFFFFu;
#pragma unroll
            for (int fn = 0; fn < 4; ++fn) {
                unsigned gcol = (unsigned)(C0 + fn * 16 + (lane & 15));
                if (acc[fm][fn][r] == m && gcol < idx) idx = gcol;
            }
#pragma unroll
            for (int off = 1; off < 16; off <<= 1) {
                unsigned o = __shfl_xor(idx, off);
                if (o < idx) idx = o;
            }
            if ((lane & 15) == 0)
                atomicMax(&rowKeys[grow], ((ull)f2ord(m) << 32) | (unsigned)(~idx));
        }
    }

    // ---- col argmax (value-first) ----
#pragma unroll
    for (int fn = 0; fn < 4; ++fn) {
        int gcol = C0 + fn * 16 + (lane & 15);
        float m = -3.4e38f;
#pragma unroll
        for (int fm = 0; fm < 4; ++fm) {
            float m01 = fmaxf(acc[fm][fn][0], acc[fm][fn][1]);
            float m23 = fmaxf(acc[fm][fn][2], acc[fm][fn][3]);
            m = fmaxf(m, fmaxf(m01, m23));
        }
        m = fmaxf(m, __shfl_xor(m, 16));
        m = fmaxf(m, __shfl_xor(m, 32));
        unsigned idx = 0xFFFFFFFFu;
#pragma unroll
        for (int fm = 0; fm < 4; ++fm) {
#pragma unroll
            for (int r = 0; r < 4; ++r) {
                unsigned grow = (unsigned)(R0 + fm * 16 + (lane >> 4) * 4 + r);
                if (acc[fm][fn][r] == m && grow < idx) idx = grow;
            }
        }
        {
            unsigned o = __shfl_xor(idx, 16);
            if (o < idx) idx = o;
            o = __shfl_xor(idx, 32);
            if (o < idx) idx = o;
        }
        if ((lane >> 4) == 0)
            atomicMax(&colKeys[gcol], ((ull)f2ord(m) << 32) | (unsigned)(~idx));
    }
}

// ---------------------------------------------------------------------------
// Kernel 3: parallel deterministic counts (int atomics).
// ---------------------------------------------------------------------------
__global__ __launch_bounds__(256) void count_kernel(const ull* __restrict__ keys, int* __restrict__ cnt)
{
    const int t = threadIdx.x;
    const int i = blockIdx.x * 256 + t;
    const int lane = t & 63;
#pragma unroll
    for (int a = 0; a < 4; ++a) {
        int s = ((~(unsigned)keys[a * N + i]) == (unsigned)i);
#pragma unroll
        for (int off = 32; off > 0; off >>= 1) s += __shfl_down(s, off);
        if (lane == 0) atomicAdd(&cnt[a], s);
    }
}

// ---------------------------------------------------------------------------
// Kernel 4: final scalars.
// ---------------------------------------------------------------------------
__global__ __launch_bounds__(64) void final_kernel(
    const float* __restrict__ diagParts, const int* __restrict__ cnt, float* __restrict__ out)
{
    const int lane = threadIdx.x;
    double vx = (double)diagParts[lane];
    double vy = (double)diagParts[64 + lane];
#pragma unroll
    for (int off = 32; off > 0; off >>= 1) {
        vx += __shfl_down(vx, off);
        vy += __shfl_down(vy, off);
    }
    if (lane == 0) {
        float invN = 1.0f / (float)N;
        out[0] = (float)(-0.5 * (vx + vy) / (double)N);
        out[1] = 0.5f * ((float)cnt[1] * invN) + (float)cnt[0] * invN;
        out[2] = 0.5f * ((float)cnt[3] * invN) + (float)cnt[2] * invN;
    }
}

// ---------------------------------------------------------------------------
extern "C" void kernel_launch(void* const* d_in, const int* in_sizes, int n_in,
                              void* d_out, int out_size, void* d_ws, size_t ws_size,
                              hipStream_t stream)
{
    (void)in_sizes; (void)n_in; (void)out_size; (void)ws_size;
    const float* x  = (const float*)d_in[0];
    const float* y  = (const float*)d_in[1];
    const float* W1 = (const float*)d_in[2];
    const float* b1 = (const float*)d_in[3];
    const float* W2 = (const float*)d_in[4];
    const float* b2 = (const float*)d_in[5];
    float* out = (float*)d_out;

    const size_t ND = (size_t)N * D;
    unsigned short* pxh = (unsigned short*)d_ws;   // 8 bf16 planes x 4 MB = 32 MB
    unsigned short* pxl = pxh + ND;
    unsigned short* pyh = pxl + ND;
    unsigned short* pyl = pyh + ND;
    unsigned short* xh  = pyl + ND;
    unsigned short* xl  = xh + ND;
    unsigned short* yh  = xl + ND;
    unsigned short* yl  = yh + ND;
    ull* keys = (ull*)(yl + ND);                   // 256 KB
    ull* rkx = keys + 0 * N;
    ull* ckx = keys + 1 * N;
    ull* rky = keys + 2 * N;
    ull* cky = keys + 3 * N;
    float* diagParts = (float*)(keys + 4 * N);     // 128 floats
    int* cnt = (int*)(diagParts + 128);            // 4 ints

    prep_kernel<<<768, 256, 0, stream>>>(x, y, W1, b1, W2, b2,
                                         pxh, pxl, pyh, pyl, xh, xl, yh, yl, keys, cnt);

    sim_argmax_mfma<<<2048, 512, 0, stream>>>(pxh, pxl, yh, yl, rkx, ckx, diagParts);
    sim_argmax_mfma<<<2048, 512, 0, stream>>>(pyh, pyl, xh, xl, rky, cky, diagParts + 64);

    count_kernel<<<32, 256, 0, stream>>>(keys, cnt);
    final_kernel<<<1, 64, 0, stream>>>(diagParts, cnt, out);
}

// Round 6
// 358.546 us; speedup vs baseline: 2.7689x; 1.0606x over previous
//
#include <hip/hip_runtime.h>

// SimSiam: N=8192, D=256, H=128, fp32 in/out.
// Sim via split-fp32 bf16 MFMA: sim = Ah·Bh^T + Al·Bh^T + Ah·Bl^T.
// All four planes co-staged per K-tile (8 steps, 48 MFMA/wave/step),
// minimal 2-phase dbuf pipeline. Planes in MFMA-tile format:
// granule16B(panel,kt,kq,m) = ((panel*8+kt)*4+kq)*128+m  (panel = 128 rows).
// Loss = mean(diag(sim)) from diagonal blocks' accumulators.

static constexpr int N = 8192;
static constexpr int D = 256;
static constexpr int H = 128;

typedef __attribute__((ext_vector_type(8))) short s16x8;
typedef __attribute__((ext_vector_type(4))) float fp32x4;
typedef unsigned long long ull;

__device__ __forceinline__ unsigned f2ord(float f) {
    unsigned u = __float_as_uint(f);
    return (u & 0x80000000u) ? ~u : (u | 0x80000000u);
}
__device__ __forceinline__ ull umax64(ull a, ull b) { return a > b ? a : b; }
__device__ __forceinline__ unsigned short bf16_rtne(float f) {
    unsigned u = __float_as_uint(f);
    unsigned r = 0x7FFFu + ((u >> 16) & 1u);
    return (unsigned short)((u + r) >> 16);
}
__device__ __forceinline__ float bf_f(unsigned short h) {
    return __uint_as_float((unsigned)h << 16);
}
__device__ __forceinline__ void split_store(float f, unsigned short* h, unsigned short* l) {
    unsigned short hb = bf16_rtne(f);
    *h = hb;
    *l = bf16_rtne(f - bf_f(hb));
}
__device__ __forceinline__ void gload16(const unsigned short* g, void* lds) {
    __builtin_amdgcn_global_load_lds(
        (const __attribute__((address_space(1))) unsigned int*)g,
        (__attribute__((address_space(3))) unsigned int*)lds, 16, 0, 0);
}
// tile-format granule index (in ushort units)
__device__ __forceinline__ size_t gidx(int panel, int kt, int kq, int m) {
    return (((size_t)(panel * 8 + kt) * 4 + kq) * 128 + m) * 8;
}

// ---------------------------------------------------------------------------
// Kernel 1 (fused prep):
//   blocks [0,512):   MLP+rownorm -> tile-format hi/lo planes (x then y)
//   blocks [512,768): key zeroing + cnt zeroing + plain rownorm of x,y
// ---------------------------------------------------------------------------
static constexpr int MLP_ROWS = 32;

__global__ __launch_bounds__(256) void prep_kernel(
    const float* __restrict__ x, const float* __restrict__ y,
    const float* __restrict__ W1, const float* __restrict__ b1,
    const float* __restrict__ W2, const float* __restrict__ b2,
    unsigned short* __restrict__ pxh, unsigned short* __restrict__ pxl,
    unsigned short* __restrict__ pyh, unsigned short* __restrict__ pyl,
    unsigned short* __restrict__ xh, unsigned short* __restrict__ xl,
    unsigned short* __restrict__ yh, unsigned short* __restrict__ yl,
    ull* __restrict__ keys, int* __restrict__ cnt)
{
    const int bid = blockIdx.x;
    const int t = threadIdx.x;

    if (bid < 512) {
        // ---------------- MLP branch ----------------
        __shared__ float sV[MLP_ROWS][D + 4];
        __shared__ float sH[MLP_ROWS][H + 4];
        __shared__ float sNrm[MLP_ROWS];

        const float* V = (bid < 256) ? x : y;
        unsigned short* Ph = (bid < 256) ? pxh : pyh;
        unsigned short* Pl = (bid < 256) ? pxl : pyl;
        const int rowBase = (bid & 255) * MLP_ROWS;

        for (int i = t; i < MLP_ROWS * (D / 4); i += 256) {
            int r = i >> 6, c4 = i & 63;
            float4 v = *reinterpret_cast<const float4*>(&V[(size_t)(rowBase + r) * D + c4 * 4]);
            sV[r][c4 * 4 + 0] = v.x; sV[r][c4 * 4 + 1] = v.y;
            sV[r][c4 * 4 + 2] = v.z; sV[r][c4 * 4 + 3] = v.w;
        }
        __syncthreads();

        {   // H = relu(V@W1 + b1)
            const int c = t & (H - 1);
            const int r0 = (t >> 7) * 16;
            float acc[16];
#pragma unroll
            for (int i = 0; i < 16; ++i) acc[i] = 0.f;
            for (int k4 = 0; k4 < D / 4; ++k4) {
                float w0 = W1[(k4 * 4 + 0) * H + c];
                float w1 = W1[(k4 * 4 + 1) * H + c];
                float w2 = W1[(k4 * 4 + 2) * H + c];
                float w3 = W1[(k4 * 4 + 3) * H + c];
#pragma unroll
                for (int i = 0; i < 16; ++i) {
                    float4 v = *reinterpret_cast<const float4*>(&sV[r0 + i][k4 * 4]);
                    acc[i] = fmaf(v.w, w3, fmaf(v.z, w2, fmaf(v.y, w1, fmaf(v.x, w0, acc[i]))));
                }
            }
            float bb = b1[c];
#pragma unroll
            for (int i = 0; i < 16; ++i) {
                float h = acc[i] + bb;
                sH[r0 + i][c] = h > 0.f ? h : 0.f;
            }
        }
        __syncthreads();

        {   // P = H@W2 + b2 -> back into sV
            const int c = t;
            float acc[MLP_ROWS];
#pragma unroll
            for (int i = 0; i < MLP_ROWS; ++i) acc[i] = 0.f;
            for (int k4 = 0; k4 < H / 4; ++k4) {
                float w0 = W2[(k4 * 4 + 0) * D + c];
                float w1 = W2[(k4 * 4 + 1) * D + c];
                float w2 = W2[(k4 * 4 + 2) * D + c];
                float w3 = W2[(k4 * 4 + 3) * D + c];
#pragma unroll
                for (int i = 0; i < MLP_ROWS; ++i) {
                    float4 v = *reinterpret_cast<const float4*>(&sH[i][k4 * 4]);
                    acc[i] = fmaf(v.w, w3, fmaf(v.z, w2, fmaf(v.y, w1, fmaf(v.x, w0, acc[i]))));
                }
            }
            float bb = b2[c];
            __syncthreads();
#pragma unroll
            for (int i = 0; i < MLP_ROWS; ++i) sV[i][c] = acc[i] + bb;
        }
        __syncthreads();

        {   // row norms
            const int wave = t >> 6, lane = t & 63;
            for (int r = wave; r < MLP_ROWS; r += 4) {
                float s = 0.f;
#pragma unroll
                for (int c = 0; c < D / 64; ++c) {
                    float v = sV[r][lane + c * 64];
                    s = fmaf(v, v, s);
                }
#pragma unroll
                for (int off = 32; off > 0; off >>= 1) s += __shfl_down(s, off);
                if (lane == 0) sNrm[r] = s;
            }
        }
        __syncthreads();

        for (int i = t; i < MLP_ROWS * (D / 4); i += 256) {
            int r = i >> 6, c4 = i & 63;
            float scale = 1.0f / fmaxf(sqrtf(sNrm[r]), 1e-12f);
            ushort4 h, l;
            split_store(sV[r][c4 * 4 + 0] * scale, &h.x, &l.x);
            split_store(sV[r][c4 * 4 + 1] * scale, &h.y, &l.y);
            split_store(sV[r][c4 * 4 + 2] * scale, &h.z, &l.z);
            split_store(sV[r][c4 * 4 + 3] * scale, &h.w, &l.w);
            int grow = rowBase + r;
            size_t g = gidx(grow >> 7, c4 >> 3, (c4 >> 1) & 3, grow & 127) + (size_t)(c4 & 1) * 4;
            *reinterpret_cast<ushort4*>(&Ph[g]) = h;
            *reinterpret_cast<ushort4*>(&Pl[g]) = l;
        }
    } else {
        // ---------------- rownorm + zeroing branch ----------------
        const int rb = bid - 512;               // 0..255
        if (t < 128) keys[rb * 128 + t] = 0ULL; // zero 32768 keys total
        if (bid == 512 && t < 4) cnt[t] = 0;
        const int wave = t >> 6, lane = t & 63;
#pragma unroll 1
        for (int i = 0; i < 16; ++i) {
            int gr = rb * 64 + wave * 16 + i;    // 0..16383
            const float* V = (gr < N) ? x : y;
            unsigned short* Vh = (gr < N) ? xh : yh;
            unsigned short* Vl = (gr < N) ? xl : yl;
            int row = gr & (N - 1);
            float4 v = *reinterpret_cast<const float4*>(&V[(size_t)row * D + lane * 4]);
            float s = fmaf(v.x, v.x, fmaf(v.y, v.y, fmaf(v.z, v.z, v.w * v.w)));
#pragma unroll
            for (int off = 32; off > 0; off >>= 1) s += __shfl_down(s, off);
            s = __shfl(s, 0);
            float scale = 1.0f / fmaxf(sqrtf(s), 1e-12f);
            ushort4 h, l;
            split_store(v.x * scale, &h.x, &l.x);
            split_store(v.y * scale, &h.y, &l.y);
            split_store(v.z * scale, &h.z, &l.z);
            split_store(v.w * scale, &h.w, &l.w);
            size_t g = gidx(row >> 7, lane >> 3, (lane >> 1) & 3, row & 127) + (size_t)(lane & 1) * 4;
            *reinterpret_cast<ushort4*>(&Vh[g]) = h;
            *reinterpret_cast<ushort4*>(&Vl[g]) = l;
        }
    }
}

// ---------------------------------------------------------------------------
// Kernel 2: sim block 128x128, 4 waves (2x2 of 64x64). Per K-tile (K=32):
// co-stage Ah/Al/Bh/Bl (32 KB), 48 MFMA/wave (hh, lh, hl). 8 steps, dbuf-2.
// ---------------------------------------------------------------------------
__global__ __launch_bounds__(256) void sim_argmax_mfma(
    const unsigned short* __restrict__ Ah, const unsigned short* __restrict__ Al,
    const unsigned short* __restrict__ Bh, const unsigned short* __restrict__ Bl,
    ull* __restrict__ rowKeys, ull* __restrict__ colKeys,
    float* __restrict__ diagParts)
{
    __shared__ s16x8 sS[2][4][512];   // 64 KB: [slot][arr Ah,Al,Bh,Bl][kq*128+m]
    __shared__ ull kbufR[128][2];     // 2 KB  row candidates (per wc)
    __shared__ ull kbufC[128][2];     // 2 KB  col candidates (per wr)
    __shared__ float sDiag[4];

    const int t = threadIdx.x;
    const int w = t >> 6, lane = t & 63;
    const int wr = w >> 1, wc = w & 1;   // 2x2 wave grid, each 64x64

    // grid 4096 = 64x64 tiles; bijective XCD swizzle (8 x 512)
    const int bid = blockIdx.x;
    const int swz = (bid & 7) * 512 + (bid >> 3);
    const int rowTile = swz & 63;        // fast -> A streams, B chunk L2-resident
    const int colTile = swz >> 6;
    const int rowBase = rowTile * 128;
    const int colBase = colTile * 128;

    fp32x4 acc[4][4];
#pragma unroll
    for (int i = 0; i < 4; ++i)
#pragma unroll
        for (int j = 0; j < 4; ++j) acc[i][j] = (fp32x4){0.f, 0.f, 0.f, 0.f};

    // per-plane granule bases for this block (ushort units)
    const unsigned short* pAh = Ah + (size_t)rowTile * 4096 * 8;
    const unsigned short* pAl = Al + (size_t)rowTile * 4096 * 8;
    const unsigned short* pBh = Bh + (size_t)colTile * 4096 * 8;
    const unsigned short* pBl = Bl + (size_t)colTile * 4096 * 8;

    // stage K-tile kt into slot: each wave stages granules [w*128,(w+1)*128) of
    // each of the 4 arrays -> 8 contiguous 1KB gload16 per wave.
#define STAGE(kt, sl)                                                           \
    do {                                                                        \
        const size_t o0 = (size_t)(kt) * 512 + w * 128 + lane;                  \
        const size_t o1 = o0 + 64;                                              \
        gload16(pAh + o0 * 8, (void*)&sS[sl][0][w * 128]);                      \
        gload16(pAh + o1 * 8, (void*)&sS[sl][0][w * 128 + 64]);                 \
        gload16(pAl + o0 * 8, (void*)&sS[sl][1][w * 128]);                      \
        gload16(pAl + o1 * 8, (void*)&sS[sl][1][w * 128 + 64]);                 \
        gload16(pBh + o0 * 8, (void*)&sS[sl][2][w * 128]);                      \
        gload16(pBh + o1 * 8, (void*)&sS[sl][2][w * 128 + 64]);                 \
        gload16(pBl + o0 * 8, (void*)&sS[sl][3][w * 128]);                      \
        gload16(pBl + o1 * 8, (void*)&sS[sl][3][w * 128 + 64]);                 \
    } while (0)

    STAGE(0, 0);

    // zero key-reduction buffers (covered by prologue barrier)
    {
        ull* kb = &kbufR[0][0];
        kb[t] = 0ULL;
        (&kbufC[0][0])[t] = 0ULL;
    }

    asm volatile("s_waitcnt vmcnt(0)" ::: "memory");
    __builtin_amdgcn_s_barrier();

    const int fBase = (lane >> 4) * 128 + (lane & 15);
    const int aBase = fBase + wr * 64;
    const int bBase = fBase + wc * 64;

#pragma unroll
    for (int kt = 0; kt < 8; ++kt) {
        const int sl = kt & 1;
        if (kt < 7) STAGE(kt + 1, sl ^ 1);   // issue-early, lands by end-of-step wait

        s16x8 ah[4], bh[4];
#pragma unroll
        for (int f = 0; f < 4; ++f) ah[f] = sS[sl][0][aBase + f * 16];
#pragma unroll
        for (int f = 0; f < 4; ++f) bh[f] = sS[sl][2][bBase + f * 16];
        __builtin_amdgcn_s_setprio(1);
#pragma unroll
        for (int fm = 0; fm < 4; ++fm)
#pragma unroll
            for (int fn = 0; fn < 4; ++fn)
                acc[fm][fn] = __builtin_amdgcn_mfma_f32_16x16x32_bf16(ah[fm], bh[fn], acc[fm][fn], 0, 0, 0);
        __builtin_amdgcn_s_setprio(0);

        {   // low-A x high-B
            s16x8 al[4];
#pragma unroll
            for (int f = 0; f < 4; ++f) al[f] = sS[sl][1][aBase + f * 16];
            __builtin_amdgcn_s_setprio(1);
#pragma unroll
            for (int fm = 0; fm < 4; ++fm)
#pragma unroll
                for (int fn = 0; fn < 4; ++fn)
                    acc[fm][fn] = __builtin_amdgcn_mfma_f32_16x16x32_bf16(al[fm], bh[fn], acc[fm][fn], 0, 0, 0);
            __builtin_amdgcn_s_setprio(0);
        }
        {   // high-A x low-B
            s16x8 bl[4];
#pragma unroll
            for (int f = 0; f < 4; ++f) bl[f] = sS[sl][3][bBase + f * 16];
            __builtin_amdgcn_s_setprio(1);
#pragma unroll
            for (int fm = 0; fm < 4; ++fm)
#pragma unroll
                for (int fn = 0; fn < 4; ++fn)
                    acc[fm][fn] = __builtin_amdgcn_mfma_f32_16x16x32_bf16(ah[fm], bl[fn], acc[fm][fn], 0, 0, 0);
            __builtin_amdgcn_s_setprio(0);
        }

        if (kt < 7) {
            asm volatile("s_waitcnt vmcnt(0)" ::: "memory");   // next tile landed
            __builtin_amdgcn_s_barrier();                       // all waves done reading sl
        }
    }
#undef STAGE

    const int R0 = wr * 64;
    const int C0 = wc * 64;

    // ---- diagonal (loss) partial ----
    if (rowTile == colTile) {
        float s = 0.f;
        if (wr == wc) {
            int dr = (lane & 15) - (lane >> 4) * 4;
            if (dr >= 0 && dr < 4) {
#pragma unroll
                for (int fm = 0; fm < 4; ++fm) s += acc[fm][fm][dr];
            }
        }
#pragma unroll
        for (int off = 32; off > 0; off >>= 1) s += __shfl_down(s, off);
        if (lane == 0) sDiag[w] = s;
        __syncthreads();
        if (t == 0) diagParts[rowTile] = ((sDiag[0] + sDiag[1]) + sDiag[2]) + sDiag[3];
    }

    // ---- row argmax candidates (value-first); C/D: col=lane&15, row=(lane>>4)*4+r
#pragma unroll
    for (int fm = 0; fm < 4; ++fm) {
#pragma unroll
        for (int r = 0; r < 4; ++r) {
            int rowLoc = R0 + fm * 16 + (lane >> 4) * 4 + r;
            float m = fmaxf(fmaxf(acc[fm][0][r], acc[fm][1][r]), fmaxf(acc[fm][2][r], acc[fm][3][r]));
#pragma unroll
            for (int off = 1; off < 16; off <<= 1) m = fmaxf(m, __shfl_xor(m, off));
            unsigned idx = 0xFFFFFFFFu;
#pragma unroll
            for (int fn = 0; fn < 4; ++fn) {
                unsigned gcol = (unsigned)(colBase + C0 + fn * 16 + (lane & 15));
                if (acc[fm][fn][r] == m && gcol < idx) idx = gcol;
            }
#pragma unroll
            for (int off = 1; off < 16; off <<= 1) {
                unsigned o = __shfl_xor(idx, off);
                if (o < idx) idx = o;
            }
            if ((lane & 15) == 0)
                kbufR[rowLoc][wc] = ((ull)f2ord(m) << 32) | (unsigned)(~idx);
        }
    }

    // ---- col argmax candidates ----
#pragma unroll
    for (int fn = 0; fn < 4; ++fn) {
        int colLoc = C0 + fn * 16 + (lane & 15);
        float m = -3.4e38f;
#pragma unroll
        for (int fm = 0; fm < 4; ++fm) {
            float m01 = fmaxf(acc[fm][fn][0], acc[fm][fn][1]);
            float m23 = fmaxf(acc[fm][fn][2], acc[fm][fn][3]);
            m = fmaxf(m, fmaxf(m01, m23));
        }
        m = fmaxf(m, __shfl_xor(m, 16));
        m = fmaxf(m, __shfl_xor(m, 32));
        unsigned idx = 0xFFFFFFFFu;
#pragma unroll
        for (int fm = 0; fm < 4; ++fm) {
#pragma unroll
            for (int r = 0; r < 4; ++r) {
                unsigned grow = (unsigned)(rowBase + R0 + fm * 16 + (lane >> 4) * 4 + r);
                if (acc[fm][fn][r] == m && grow < idx) idx = grow;
            }
        }
        {
            unsigned o = __shfl_xor(idx, 16);
            if (o < idx) idx = o;
            o = __shfl_xor(idx, 32);
            if (o < idx) idx = o;
        }
        if ((lane >> 4) == 0)
            kbufC[colLoc][wr] = ((ull)f2ord(m) << 32) | (unsigned)(~idx);
    }

    __syncthreads();

    // ---- one global atomic per row / col ----
    if (t < 128) {
        ull best = umax64(kbufR[t][0], kbufR[t][1]);
        atomicMax(&rowKeys[rowBase + t], best);
    } else {
        int c = t - 128;
        ull best = umax64(kbufC[c][0], kbufC[c][1]);
        atomicMax(&colKeys[colBase + c], best);
    }
}

// ---------------------------------------------------------------------------
// Kernel 3: parallel deterministic counts (int atomics).
// ---------------------------------------------------------------------------
__global__ __launch_bounds__(256) void count_kernel(const ull* __restrict__ keys, int* __restrict__ cnt)
{
    const int t = threadIdx.x;
    const int i = blockIdx.x * 256 + t;
    const int lane = t & 63;
#pragma unroll
    for (int a = 0; a < 4; ++a) {
        int s = ((~(unsigned)keys[a * N + i]) == (unsigned)i);
#pragma unroll
        for (int off = 32; off > 0; off >>= 1) s += __shfl_down(s, off);
        if (lane == 0) atomicAdd(&cnt[a], s);
    }
}

// ---------------------------------------------------------------------------
// Kernel 4: final scalars.
// ---------------------------------------------------------------------------
__global__ __launch_bounds__(64) void final_kernel(
    const float* __restrict__ diagParts, const int* __restrict__ cnt, float* __restrict__ out)
{
    const int lane = threadIdx.x;
    double vx = (double)diagParts[lane];
    double vy = (double)diagParts[64 + lane];
#pragma unroll
    for (int off = 32; off > 0; off >>= 1) {
        vx += __shfl_down(vx, off);
        vy += __shfl_down(vy, off);
    }
    if (lane == 0) {
        float invN = 1.0f / (float)N;
        out[0] = (float)(-0.5 * (vx + vy) / (double)N);
        out[1] = 0.5f * ((float)cnt[1] * invN) + (float)cnt[0] * invN;
        out[2] = 0.5f * ((float)cnt[3] * invN) + (float)cnt[2] * invN;
    }
}

// ---------------------------------------------------------------------------
extern "C" void kernel_launch(void* const* d_in, const int* in_sizes, int n_in,
                              void* d_out, int out_size, void* d_ws, size_t ws_size,
                              hipStream_t stream)
{
    (void)in_sizes; (void)n_in; (void)out_size; (void)ws_size;
    const float* x  = (const float*)d_in[0];
    const float* y  = (const float*)d_in[1];
    const float* W1 = (const float*)d_in[2];
    const float* b1 = (const float*)d_in[3];
    const float* W2 = (const float*)d_in[4];
    const float* b2 = (const float*)d_in[5];
    float* out = (float*)d_out;

    const size_t ND = (size_t)N * D;
    unsigned short* pxh = (unsigned short*)d_ws;   // 8 bf16 planes x 4 MB = 32 MB
    unsigned short* pxl = pxh + ND;
    unsigned short* pyh = pxl + ND;
    unsigned short* pyl = pyh + ND;
    unsigned short* xh  = pyl + ND;
    unsigned short* xl  = xh + ND;
    unsigned short* yh  = xl + ND;
    unsigned short* yl  = yh + ND;
    ull* keys = (ull*)(yl + ND);                   // 256 KB
    ull* rkx = keys + 0 * N;
    ull* ckx = keys + 1 * N;
    ull* rky = keys + 2 * N;
    ull* cky = keys + 3 * N;
    float* diagParts = (float*)(keys + 4 * N);     // 128 floats
    int* cnt = (int*)(diagParts + 128);            // 4 ints

    prep_kernel<<<768, 256, 0, stream>>>(x, y, W1, b1, W2, b2,
                                         pxh, pxl, pyh, pyl, xh, xl, yh, yl, keys, cnt);

    sim_argmax_mfma<<<4096, 256, 0, stream>>>(pxh, pxl, yh, yl, rkx, ckx, diagParts);
    sim_argmax_mfma<<<4096, 256, 0, stream>>>(pyh, pyl, xh, xl, rky, cky, diagParts + 64);

    count_kernel<<<32, 256, 0, stream>>>(keys, cnt);
    final_kernel<<<1, 64, 0, stream>>>(diagParts, cnt, out);
}